// Round 1
// baseline (466.347 us; speedup 1.0000x reference)
//
#include <hip/hip_runtime.h>
#include <hip/hip_bf16.h>

// ---------------------------------------------------------------------------
// LATTE heterogeneous GNN layer (gene/protein).
// R10: CSR record is now {dst, w} (8B). scatter3 computes
//      w = expf((tl+tr)*sharp) edge-parallel (it already touches both
//      endpoints), so gather_combine's record phase, expf, and ALL
//      ds_bpermute broadcasts are gone. Gather inner loop per edge:
//      uniform 8B record load (half-wave same-address broadcast, L1-hot)
//      -> 8B row load (32-bit offset) -> 4 cvt + 4 FMA. 4-wide unroll
//      (8 edges/wave/iter) for MLP. Denominator reduce: 6-step shuffle
//      tree -> single xor-32 fold (per-half lanes hold identical sums).
// ---------------------------------------------------------------------------

typedef __attribute__((ext_vector_type(8))) short short8;   // 8 bf16
typedef __attribute__((ext_vector_type(4))) float floatx4;  // 4 f32 acc

__device__ __forceinline__ void gload16(const void* g, void* l) {
  __builtin_amdgcn_global_load_lds(
      (const __attribute__((address_space(1))) void*)g,
      (__attribute__((address_space(3))) void*)l, 16, 0, 0);
}

__device__ __forceinline__ ushort f2b(float x) {
  __hip_bfloat16 h = __float2bfloat16(x);
  return *reinterpret_cast<ushort*>(&h);
}
__device__ __forceinline__ float b2f_lo(unsigned v) { return __uint_as_float(v << 16); }
__device__ __forceinline__ float b2f_hi(unsigned v) { return __uint_as_float(v & 0xffff0000u); }

// ---------------- batched fp32 -> bf16 convert (8 tensors) -----------------
struct CvtArgs {
  const float* src[8];
  ushort* dst[8];
  int valid[8];
  int total[8];
  int bstart[9];
};
__global__ __launch_bounds__(256) void cvt_multi(CvtArgs a) {
  int b = blockIdx.x;
  int e = 0;
#pragma unroll
  for (int j = 1; j < 8; ++j)
    if (b >= a.bstart[j]) e = j;
  int i = ((b - a.bstart[e]) * 256 + threadIdx.x) * 4;
  if (i >= a.total[e]) return;
  float4 v = make_float4(0.f, 0.f, 0.f, 0.f);
  if (i < a.valid[e]) v = *(const float4*)(a.src[e] + i);
  ushort4 o;
  o.x = f2b(v.x); o.y = f2b(v.y); o.z = f2b(v.z); o.w = f2b(v.w);
  *(ushort4*)(a.dst[e] + i) = o;
}

// ------------- fused l/r projection: [NPAD,256]bf16 @ [256,256]^T ----------
struct ProjArgs {
  const ushort* xb[2];
  const ushort* Wb[2];
  const float* bl[2];
  const float* br[2];
  ushort* lb[2];
  ushort* rb[2];
  int N[2];
};
__global__ __launch_bounds__(256) void proj_lr_mfma(ProjArgs g) {
  const int ty = blockIdx.z;
  const ushort* xb = g.xb[ty];
  __shared__ ushort As[128 * 32];
  __shared__ ushort Bs[128 * 32];
  const int tid = threadIdx.x;
  const int lane = tid & 63;
  const int wave = tid >> 6;
  const int wm = wave & 1, wn = wave >> 1;
  const int rowBase = blockIdx.x * 128;
  const int colHalf = blockIdx.y;
  const ushort* Wbase = g.Wb[ty] + (size_t)colHalf * 128 * 256;

  floatx4 acc[4][4] = {};

  const int srow = tid >> 2, schk = tid & 3;
  for (int k0 = 0; k0 < 256; k0 += 32) {
#pragma unroll
    for (int i = 0; i < 2; ++i) {
      gload16(xb + (size_t)(rowBase + srow + i * 64) * 256 + k0 + schk * 8,
              &As[(tid + i * 256) * 8]);
      gload16(Wbase + (size_t)(srow + i * 64) * 256 + k0 + schk * 8,
              &Bs[(tid + i * 256) * 8]);
    }
    __syncthreads();
    short8 bf[4];
#pragma unroll
    for (int nt = 0; nt < 4; ++nt)
      bf[nt] = *(const short8*)&Bs[(wn * 64 + nt * 16 + (lane & 15)) * 32 + (lane >> 4) * 8];
#pragma unroll
    for (int mt = 0; mt < 4; ++mt) {
      short8 a = *(const short8*)&As[(wm * 64 + mt * 16 + (lane & 15)) * 32 + (lane >> 4) * 8];
#pragma unroll
      for (int nt = 0; nt < 4; ++nt)
        acc[mt][nt] = __builtin_amdgcn_mfma_f32_16x16x32_bf16(a, bf[nt], acc[mt][nt], 0, 0, 0);
    }
    __syncthreads();
  }

  const int N = g.N[ty];
  const float* bias = colHalf ? g.br[ty] : g.bl[ty];
  ushort* outp = colHalf ? g.rb[ty] : g.lb[ty];
#pragma unroll
  for (int mt = 0; mt < 4; ++mt)
#pragma unroll
    for (int nt = 0; nt < 4; ++nt) {
      int col = wn * 64 + nt * 16 + (lane & 15);
      float bv = bias[col];
#pragma unroll
      for (int vi = 0; vi < 4; ++vi) {
        int row = rowBase + wm * 64 + mt * 16 + (lane >> 4) * 4 + vi;
        if (row < N) outp[(size_t)row * 128 + col] = f2b(acc[mt][nt][vi] + bv);
      }
    }
}

// ------------- batched attention projection (4 GEMMs), grid.y = entry ------
struct AttnArgs {
  const ushort* Ab[4];
  const ushort* Wb[4];
  const float* bias[4];
  float* out[4];
  int N[4];
  int BN[4];
};
__global__ __launch_bounds__(256) void attn_proj_multi(AttnArgs g) {
  const int ei = blockIdx.y;
  const ushort* Ab = g.Ab[ei];
  const ushort* Wb = g.Wb[ei];
  const int N = g.N[ei], BN = g.BN[ei];
  const int NB = BN >> 4;
  __shared__ ushort As[128 * 32];
  __shared__ ushort Ws[64 * 128];
  const int tid = threadIdx.x;
  const int lane = tid & 63;
  const int wave = tid >> 6;
  const int rowBase = blockIdx.x * 128;

  for (int i = 0; i < NB; ++i) {
    int idx = tid + i * 256;
    gload16(Wb + (size_t)idx * 8, &Ws[idx * 8]);
  }

  floatx4 acc[2][4] = {};
  for (int k0 = 0; k0 < 128; k0 += 32) {
#pragma unroll
    for (int i = 0; i < 2; ++i) {
      int t = tid + i * 256;
      gload16(Ab + (size_t)(rowBase + (t >> 2)) * 128 + k0 + (t & 3) * 8, &As[t * 8]);
    }
    __syncthreads();
    short8 bf[4];
#pragma unroll
    for (int nt = 0; nt < 4; ++nt)
      if (nt < NB)
        bf[nt] = *(const short8*)&Ws[(nt * 16 + (lane & 15)) * 128 + k0 + (lane >> 4) * 8];
#pragma unroll
    for (int mt = 0; mt < 2; ++mt) {
      short8 a = *(const short8*)&As[(wave * 32 + mt * 16 + (lane & 15)) * 32 + (lane >> 4) * 8];
#pragma unroll
      for (int nt = 0; nt < 4; ++nt)
        if (nt < NB)
          acc[mt][nt] = __builtin_amdgcn_mfma_f32_16x16x32_bf16(a, bf[nt], acc[mt][nt], 0, 0, 0);
    }
    __syncthreads();
  }
  const float* bias = g.bias[ei];
  float* out = g.out[ei];
#pragma unroll
  for (int mt = 0; mt < 2; ++mt)
#pragma unroll
    for (int nt = 0; nt < 4; ++nt) {
      if (nt >= NB) continue;
      int col = nt * 16 + (lane & 15);
      float bv = bias[col];
#pragma unroll
      for (int vi = 0; vi < 4; ++vi) {
        int row = rowBase + wave * 32 + mt * 16 + (lane >> 4) * 4 + vi;
        if (row < N) out[(size_t)row * BN + col] = acc[mt][nt][vi] + bv;
      }
    }
}

// ------- batched per-node tanh-dot (6 entries) ----------------------------
struct TanhArgs {
  const float* a[6];
  const float* q[6];
  float* out[6];
  int stride[6];
  int N[6];
  int bstart[7];
};
__global__ __launch_bounds__(256) void tanh_multi(TanhArgs t) {
  int b = blockIdx.x;
  int e = 0;
#pragma unroll
  for (int j = 1; j < 6; ++j)
    if (b >= t.bstart[j]) e = j;
  int lane32 = threadIdx.x & 31;
  int node = (b - t.bstart[e]) * 8 + (threadIdx.x >> 5);
  if (node >= t.N[e]) return;
  float p = tanhf(t.a[e][(size_t)node * t.stride[e] + lane32]) * t.q[e][lane32];
#pragma unroll
  for (int m = 16; m >= 1; m >>= 1) p += __shfl_xor(p, m, 32);
  if (lane32 == 0) t.out[e][node] = p;
}

// ------- hist + rank: deg count and per-edge rank (coalesced) -------------
__global__ __launch_bounds__(256) void hist3_kernel(
    const int* __restrict__ e0, const int* __restrict__ e1,
    const int* __restrict__ e2, int* __restrict__ deg,
    int* __restrict__ rank, int E, int NG) {
  int e = blockIdx.x * 256 + threadIdx.x;
  if (e >= 3 * E) return;
  int mp = (e >= 2 * E) ? 2 : ((e >= E) ? 1 : 0);
  int el = e - mp * E;
  const int* ep = (mp == 0) ? e0 : (mp == 1) ? e1 : e2;
  int segb = (mp == 2) ? 2 * NG : mp * NG;
  rank[e] = atomicAdd(&deg[segb + ep[el]], 1);
}

// ------- hierarchical scan: A) tile scan, B) partials, C) add prefix ------
__global__ __launch_bounds__(256) void scanA_kernel(
    const int* __restrict__ deg, int* __restrict__ offsets,
    int* __restrict__ tile_tot, int n) {
  __shared__ int wtot[4];
  const int t = threadIdx.x;
  const int base = blockIdx.x * 2048 + t * 8;
  int v[8], pre[8], s = 0;
#pragma unroll
  for (int j = 0; j < 8; ++j) {
    v[j] = (base + j < n) ? deg[base + j] : 0;
    pre[j] = s;
    s += v[j];
  }
  const int lane = t & 63, wv = t >> 6;
  int x = s;
#pragma unroll
  for (int o = 1; o < 64; o <<= 1) {
    int u = __shfl_up(x, o, 64);
    if (lane >= o) x += u;
  }
  if (lane == 63) wtot[wv] = x;
  __syncthreads();
  int wpre = 0;
#pragma unroll
  for (int j = 0; j < 4; ++j) wpre += (j < wv) ? wtot[j] : 0;
  int excl = wpre + x - s;
#pragma unroll
  for (int j = 0; j < 8; ++j)
    if (base + j < n) offsets[base + j] = excl + pre[j];
  if (t == 255) tile_tot[blockIdx.x] = wpre + x;
}

__global__ __launch_bounds__(256) void scanB_kernel(
    const int* __restrict__ tile_tot, int* __restrict__ tile_pre,
    int* __restrict__ offsets, int T, int n) {
  __shared__ int wtot[4];
  const int t = threadIdx.x;
  int v = (t < T) ? tile_tot[t] : 0;
  const int lane = t & 63, wv = t >> 6;
  int x = v;
#pragma unroll
  for (int o = 1; o < 64; o <<= 1) {
    int u = __shfl_up(x, o, 64);
    if (lane >= o) x += u;
  }
  if (lane == 63) wtot[wv] = x;
  __syncthreads();
  int wpre = 0;
#pragma unroll
  for (int j = 0; j < 4; ++j) wpre += (j < wv) ? wtot[j] : 0;
  if (t < T) tile_pre[t] = wpre + x - v;
  if (t == 255) offsets[n] = wpre + x;  // grand total
}

__global__ __launch_bounds__(256) void scanC_kernel(
    int* __restrict__ offsets, const int* __restrict__ tile_pre, int n) {
  const int add = tile_pre[blockIdx.x];
  const int base = blockIdx.x * 2048 + threadIdx.x * 8;
#pragma unroll
  for (int j = 0; j < 8; ++j)
    if (base + j < n) offsets[base + j] += add;
}

// ------- scatter3: pos = offsets[node] + rank[e]; writes {dst, w} ---------
// w = expf((tl[head]+tr[tail])*sharp) computed here, edge-parallel: this
// kernel is massively latency-tolerant, and it removes expf + the tr3
// gather + the whole record/broadcast phase from gather_combine.
__global__ __launch_bounds__(256) void scatter3_kernel(
    const int* __restrict__ e0, const int* __restrict__ e1,
    const int* __restrict__ e2, const int* __restrict__ rank,
    const int* __restrict__ offsets,
    const float* __restrict__ tl3, const float* __restrict__ tr3,
    const float* __restrict__ sharp, int2* __restrict__ recs,
    int E, int NG, int NP) {
  int e = blockIdx.x * 256 + threadIdx.x;
  if (e >= 3 * E) return;
  int mp = (e >= 2 * E) ? 2 : ((e >= E) ? 1 : 0);
  int el = e - mp * E;
  const int* ep = (mp == 0) ? e0 : (mp == 1) ? e1 : e2;
  int s = ep[el], d = ep[el + E];
  int hb = (mp == 2) ? 2 * NG : mp * NG;                 // head/offsets base
  int tb = (mp == 0) ? 0 : (mp == 1) ? NG : NG + NP;     // tr3 segment base
  // |tl+tr| <= sum|qw| ~ 10 -> exp safe in fp32 without max-shift.
  float w = expf((tl3[hb + s] + tr3[tb + d]) * sharp[mp]);
  recs[offsets[hb + s] + rank[e]] = make_int2(d, __float_as_int(w));
}

// ------- per-segment weighted gather over {dst,w} records -----------------
// Half-wave per edge row (32 lanes x 8B). Per iteration each half handles
// 4 consecutive edges (8/wave): 4 uniform 8B record loads (same-address
// broadcast, L1-hot: a node's records are contiguous) + 4 row loads with
// 32-bit offsets + 16 cvt + 16 FMA. No cross-lane ops in the loop.
__device__ __forceinline__ void seg_accum(
    const ushort* __restrict__ rt, const int2* __restrict__ recs,
    int j0, int j1, int half, unsigned coloff,
    float& ac0, float& ac1, float& ac2, float& ac3, float& ds) {
  for (int b = j0; b < j1; b += 8) {
    const int i0 = b + (half << 2);
    int2 rc[4];
#pragma unroll
    for (int p = 0; p < 4; ++p) {
      int ii = i0 + p;
      rc[p] = recs[ii < j1 ? ii : j1 - 1];  // clamp: dup row is L1-hit
    }
    float w[4];
    uint2 v[4];
#pragma unroll
    for (int p = 0; p < 4; ++p) {
      w[p] = (i0 + p < j1) ? __int_as_float(rc[p].y) : 0.f;
      unsigned off = ((unsigned)rc[p].x << 8) + coloff;  // d*256B fits u32
      v[p] = *(const uint2*)((const char*)rt + off);
    }
#pragma unroll
    for (int p = 0; p < 4; ++p) {
      ac0 += b2f_lo(v[p].x) * w[p];
      ac1 += b2f_hi(v[p].x) * w[p];
      ac2 += b2f_lo(v[p].y) * w[p];
      ac3 += b2f_hi(v[p].y) * w[p];
      ds += w[p];
    }
  }
}

// ------- fused gather + relation combine: wave per OUTPUT node ------------
__global__ __launch_bounds__(256) void gather_combine(
    const ushort* __restrict__ rb_gene, const ushort* __restrict__ rb_prot,
    const ushort* __restrict__ lb_gene, const ushort* __restrict__ lb_prot,
    const int* __restrict__ offsets, const int2* __restrict__ recs,
    const float* __restrict__ cgW, const float* __restrict__ cgb,
    const float* __restrict__ cpW, const float* __restrict__ cpb,
    float* __restrict__ out_gene, float* __restrict__ out_prot,
    int NG, int NP) {
  const int lane = threadIdx.x & 63;
  const int half = lane >> 5;
  const int l32 = lane & 31;
  const int node = blockIdx.x * 4 + (threadIdx.x >> 6);
  if (node >= NG + NP) return;
  const bool isGene = node < NG;
  const unsigned coloff = (unsigned)l32 << 3;

  // hoist both relations' segment bounds (wave-uniform s_loads, early)
  const int h0 = isGene ? node : NG + node;  // gg for genes / pp for prots
  const int j0a = offsets[h0], j1a = offsets[h0 + 1];
  int j0b = 0, j1b = 0;
  if (isGene) { j0b = offsets[NG + node]; j1b = offsets[NG + node + 1]; }

  float a0[4] = {0.f, 0.f, 0.f, 0.f};
  float a1[4] = {0.f, 0.f, 0.f, 0.f};
  float ds0 = 0.f, ds1 = 0.f;

  const ushort* rtA = isGene ? rb_gene : rb_prot;
  seg_accum(rtA, recs, j0a, j1a, half, coloff, a0[0], a0[1], a0[2], a0[3], ds0);
  if (isGene)
    seg_accum(rb_prot, recs, j0b, j1b, half, coloff, a1[0], a1[1], a1[2], a1[3], ds1);

  // fold halves: each half holds its own edges' partials for cols l32*4..;
  // per-half lanes hold identical ds -> single xor-32 completes the sum.
#pragma unroll
  for (int c = 0; c < 4; ++c) {
    a0[c] += __shfl_xor(a0[c], 32, 64);
    a1[c] += __shfl_xor(a1[c], 32, 64);
  }
  ds0 += __shfl_xor(ds0, 32, 64);
  ds1 += __shfl_xor(ds1, 32, 64);

  const float inv0 = 1.f / (ds0 + 1e-16f);
  const float inv1 = 1.f / (ds1 + 1e-16f);
  float g0[4], g1[4], self[4];
#pragma unroll
  for (int c = 0; c < 4; ++c) { g0[c] = a0[c] * inv0; g1[c] = a1[c] * inv1; }
  {
    const ushort* lbp = isGene ? lb_gene + (size_t)node * 128
                               : lb_prot + (size_t)(node - NG) * 128;
    uint2 sv = *(const uint2*)(lbp + l32 * 4);
    self[0] = b2f_lo(sv.x); self[1] = b2f_hi(sv.x);
    self[2] = b2f_lo(sv.y); self[3] = b2f_hi(sv.y);
  }

  const float* cW = isGene ? cgW : cpW;
  const float cb = isGene ? cgb[0] : cpb[0];
  const float4 w4 = *(const float4*)(cW + l32 * 4);
  float p0 = g0[0] * w4.x + g0[1] * w4.y + g0[2] * w4.z + g0[3] * w4.w;
  float p1 = g1[0] * w4.x + g1[1] * w4.y + g1[2] * w4.z + g1[3] * w4.w;
  float ps = self[0] * w4.x + self[1] * w4.y + self[2] * w4.z + self[3] * w4.w;
#pragma unroll
  for (int m = 16; m >= 1; m >>= 1) {  // halves duplicate; reduce 32 cols
    p0 += __shfl_xor(p0, m, 64);
    p1 += __shfl_xor(p1, m, 64);
    ps += __shfl_xor(ps, m, 64);
  }
  const float s0 = p0 + cb, s1 = p1 + cb, ss = ps + cb;
  const float mx = isGene ? fmaxf(fmaxf(s0, s1), ss) : fmaxf(s0, ss);
  const float e0 = expf(s0 - mx);
  const float e1 = isGene ? expf(s1 - mx) : 0.f;
  const float es = expf(ss - mx);
  const float sum = e0 + e1 + es;
  const float b0 = e0 / sum, b1 = e1 / sum, bs = es / sum;

  if (half == 0) {
    float4 o;
    o.x = fmaxf(g0[0] * b0 + g1[0] * b1 + self[0] * bs, 0.f);
    o.y = fmaxf(g0[1] * b0 + g1[1] * b1 + self[1] * bs, 0.f);
    o.z = fmaxf(g0[2] * b0 + g1[2] * b1 + self[2] * bs, 0.f);
    o.w = fmaxf(g0[3] * b0 + g1[3] * b1 + self[3] * bs, 0.f);
    float* op = isGene ? out_gene + (size_t)node * 128
                       : out_prot + (size_t)(node - NG) * 128;
    *(float4*)(op + l32 * 4) = o;
  }
}

// ---------------------------------------------------------------------------
extern "C" void kernel_launch(void* const* d_in, const int* in_sizes, int n_in,
                              void* d_out, int out_size, void* d_ws,
                              size_t ws_size, hipStream_t stream) {
  const float* x_gene  = (const float*)d_in[0];
  const float* x_prot  = (const float*)d_in[1];
  const float* Wl_gene = (const float*)d_in[2];
  const float* bl_gene = (const float*)d_in[3];
  const float* Wr_gene = (const float*)d_in[4];
  const float* br_gene = (const float*)d_in[5];
  const float* Wl_prot = (const float*)d_in[6];
  const float* bl_prot = (const float*)d_in[7];
  const float* Wr_prot = (const float*)d_in[8];
  const float* br_prot = (const float*)d_in[9];
  const float* alW     = (const float*)d_in[10];  // [3,32,128] contiguous
  const float* alb     = (const float*)d_in[11];  // [3,32] contiguous
  const float* arW     = (const float*)d_in[12];
  const float* arb     = (const float*)d_in[13];
  const float* qw      = (const float*)d_in[14];  // [3,64,1]
  const float* sharp   = (const float*)d_in[15];
  const float* cgW     = (const float*)d_in[16];
  const float* cgb     = (const float*)d_in[17];
  const float* cpW     = (const float*)d_in[18];
  const float* cpb     = (const float*)d_in[19];
  const int* e_gg      = (const int*)d_in[20];
  const int* e_gp      = (const int*)d_in[21];
  const int* e_pp      = (const int*)d_in[22];

  const int NG = in_sizes[0] / 256;
  const int NP = in_sizes[1] / 256;
  const int E  = in_sizes[20] / 2;
  const int NPG = (NG + 127) & ~127;
  const int NPP = (NP + 127) & ~127;
  const int NT = 2 * NG + NP;          // concatenated head-node space
  const int NR = NG + 2 * NP;          // concatenated tail-node space (tr)

  char* base = (char*)d_ws;
  size_t off = 0;
  auto alloc = [&](size_t bytes) {
    void* p = base + off;
    off = (off + bytes + 255) & ~(size_t)255;
    return p;
  };
  ushort* xb_gene = (ushort*)alloc((size_t)NPG * 256 * 2);
  ushort* xb_prot = (ushort*)alloc((size_t)NPP * 256 * 2);
  // aliases over xb region (valid after proj phase; 96*4=384 < 512 B/row)
  float* al_gene = (float*)xb_gene;                 // [NPG,64] = al0|al1
  float* ar_gene = al_gene + (size_t)NPG * 64;      // [NPG,32]
  float* al_prot = ar_gene + (size_t)NPG * 32;      // [NPP,32]
  float* ar_prot = al_prot + (size_t)NPP * 32;      // [NPP,64] = ar1|ar2

  ushort* Wlr_gene = (ushort*)alloc(256 * 256 * 2);
  ushort* Wlr_prot = (ushort*)alloc(256 * 256 * 2);
  ushort* alWb     = (ushort*)alloc(96 * 128 * 2);
  ushort* arWb     = (ushort*)alloc(96 * 128 * 2);
  ushort* lb_gene  = (ushort*)alloc((size_t)NPG * 128 * 2);
  ushort* rb_gene  = (ushort*)alloc((size_t)NPG * 128 * 2);
  ushort* lb_prot  = (ushort*)alloc((size_t)NPP * 128 * 2);
  ushort* rb_prot  = (ushort*)alloc((size_t)NPP * 128 * 2);
  int*    deg      = (int*)alloc((size_t)NT * 4);
  int*    offsets  = (int*)alloc((size_t)(NT + 1) * 4);
  const int TILES  = (NT + 2047) / 2048;
  int*    tile_tot = (int*)alloc((size_t)TILES * 4);
  int*    tile_pre = (int*)alloc((size_t)TILES * 4);
  int*    rank     = (int*)alloc((size_t)(3 * E) * 4);
  int2*   recs     = (int2*)alloc((size_t)(3 * E) * sizeof(int2));
  float*  tl3      = (float*)alloc((size_t)NT * 4);
  float*  tr3      = (float*)alloc((size_t)NR * 4);

  float* out_gene = (float*)d_out;
  float* out_prot = out_gene + (size_t)NG * 128;

  dim3 blk(256);

  // ---- 0) batched bf16 conversions (1 dispatch) ----
  {
    CvtArgs a;
    const float* srcs[8] = {x_gene, x_prot, Wl_gene, Wr_gene, Wl_prot, Wr_prot, alW, arW};
    ushort* dsts[8] = {xb_gene, xb_prot, Wlr_gene, Wlr_gene + 128 * 256,
                       Wlr_prot, Wlr_prot + 128 * 256, alWb, arWb};
    int valids[8] = {NG * 256, NP * 256, 128 * 256, 128 * 256, 128 * 256, 128 * 256, 96 * 128, 96 * 128};
    int totals[8] = {NPG * 256, NPP * 256, 128 * 256, 128 * 256, 128 * 256, 128 * 256, 96 * 128, 96 * 128};
    int b = 0;
    for (int j = 0; j < 8; ++j) {
      a.src[j] = srcs[j]; a.dst[j] = dsts[j];
      a.valid[j] = valids[j]; a.total[j] = totals[j];
      a.bstart[j] = b;
      b += (totals[j] / 4 + 255) / 256;
    }
    a.bstart[8] = b;
    cvt_multi<<<b, blk, 0, stream>>>(a);
  }

  // ---- 1) fused l/r projections, both node types (1 dispatch) ----
  {
    ProjArgs p;
    p.xb[0] = xb_gene; p.xb[1] = xb_prot;
    p.Wb[0] = Wlr_gene; p.Wb[1] = Wlr_prot;
    p.bl[0] = bl_gene; p.bl[1] = bl_prot;
    p.br[0] = br_gene; p.br[1] = br_prot;
    p.lb[0] = lb_gene; p.lb[1] = lb_prot;
    p.rb[0] = rb_gene; p.rb[1] = rb_prot;
    p.N[0] = NG; p.N[1] = NP;
    proj_lr_mfma<<<dim3(NPG / 128, 2, 2), blk, 0, stream>>>(p);
  }

  // ---- 2) batched attention projections (1 dispatch) ----
  {
    AttnArgs a;
    a.Ab[0] = lb_gene; a.Wb[0] = alWb;            a.bias[0] = alb;      a.out[0] = al_gene; a.N[0] = NG; a.BN[0] = 64;
    a.Ab[1] = rb_gene; a.Wb[1] = arWb;            a.bias[1] = arb;      a.out[1] = ar_gene; a.N[1] = NG; a.BN[1] = 32;
    a.Ab[2] = lb_prot; a.Wb[2] = alWb + 64 * 128; a.bias[2] = alb + 64; a.out[2] = al_prot; a.N[2] = NP; a.BN[2] = 32;
    a.Ab[3] = rb_prot; a.Wb[3] = arWb + 32 * 128; a.bias[3] = arb + 32; a.out[3] = ar_prot; a.N[3] = NP; a.BN[3] = 64;
    attn_proj_multi<<<dim3(NPG / 128, 4), blk, 0, stream>>>(a);
  }

  // ---- 3) batched per-node tanh-dot scalars (1 dispatch) ----
  {
    TanhArgs t;
    const float* as[6] = {al_gene, ar_gene, al_gene + 32, ar_prot, al_prot, ar_prot + 32};
    const float* qs[6] = {qw + 0, qw + 32, qw + 64, qw + 96, qw + 128, qw + 160};
    float* outs[6] = {tl3, tr3, tl3 + NG, tr3 + NG, tl3 + 2 * NG, tr3 + NG + NP};
    int strides[6] = {64, 32, 64, 64, 32, 64};
    int Ns[6] = {NG, NG, NG, NP, NP, NP};
    int b = 0;
    for (int j = 0; j < 6; ++j) {
      t.a[j] = as[j]; t.q[j] = qs[j]; t.out[j] = outs[j];
      t.stride[j] = strides[j]; t.N[j] = Ns[j];
      t.bstart[j] = b;
      b += (Ns[j] + 7) / 8;
    }
    t.bstart[6] = b;
    tanh_multi<<<b, blk, 0, stream>>>(t);
  }

  // ---- 4) CSR build (hist+rank -> scan -> scatter{dst,w}) ----
  const int gridE3 = (3 * E + 255) / 256;
  hipMemsetAsync(deg, 0, (size_t)NT * sizeof(int), stream);
  hist3_kernel<<<gridE3, blk, 0, stream>>>(e_gg, e_gp, e_pp, deg, rank, E, NG);
  scanA_kernel<<<TILES, blk, 0, stream>>>(deg, offsets, tile_tot, NT);
  scanB_kernel<<<1, blk, 0, stream>>>(tile_tot, tile_pre, offsets, TILES, NT);
  scanC_kernel<<<TILES, blk, 0, stream>>>(offsets, tile_pre, NT);
  scatter3_kernel<<<gridE3, blk, 0, stream>>>(e_gg, e_gp, e_pp, rank, offsets,
                                              tl3, tr3, sharp, recs, E, NG, NP);

  // ---- 5) fused gather + relation combine (1 dispatch) ----
  gather_combine<<<(NG + NP + 3) / 4, blk, 0, stream>>>(
      rb_gene, rb_prot, lb_gene, lb_prot, offsets, recs,
      cgW, cgb, cpW, cpb, out_gene, out_prot, NG, NP);
}

// Round 3
// 460.806 us; speedup vs baseline: 1.0120x; 1.0120x over previous
//
#include <hip/hip_runtime.h>
#include <hip/hip_bf16.h>

// ---------------------------------------------------------------------------
// LATTE heterogeneous GNN layer (gene/protein).
// R11 (resubmit; R2 bench was a GPU-acquisition timeout, no data):
//      gather goes quarter-wave: 16 lanes x 16B (uint4) per edge row, so
//      every scalar instruction (record addr, clamp/select, converts) is
//      amortized over 4 edges/wave-inst (~6 VALU/edge vs ~19 in R10).
//      scatter3 stores d*256 in the record -> row address is one u32 add.
//      Gene waves process gg+gp segments in ONE fused loop (independent
//      acc sets) so both relations' record/row loads overlap -> 2x MLP on
//      the offsets->record->row dependent chain. Proteins: single segment,
//      4 edges/quarter unroll (16 edges/wave/iter).
// ---------------------------------------------------------------------------

typedef __attribute__((ext_vector_type(8))) short short8;   // 8 bf16
typedef __attribute__((ext_vector_type(4))) float floatx4;  // 4 f32 acc

__device__ __forceinline__ void gload16(const void* g, void* l) {
  __builtin_amdgcn_global_load_lds(
      (const __attribute__((address_space(1))) void*)g,
      (__attribute__((address_space(3))) void*)l, 16, 0, 0);
}

__device__ __forceinline__ ushort f2b(float x) {
  __hip_bfloat16 h = __float2bfloat16(x);
  return *reinterpret_cast<ushort*>(&h);
}
__device__ __forceinline__ float b2f_lo(unsigned v) { return __uint_as_float(v << 16); }
__device__ __forceinline__ float b2f_hi(unsigned v) { return __uint_as_float(v & 0xffff0000u); }

// ---------------- batched fp32 -> bf16 convert (8 tensors) -----------------
struct CvtArgs {
  const float* src[8];
  ushort* dst[8];
  int valid[8];
  int total[8];
  int bstart[9];
};
__global__ __launch_bounds__(256) void cvt_multi(CvtArgs a) {
  int b = blockIdx.x;
  int e = 0;
#pragma unroll
  for (int j = 1; j < 8; ++j)
    if (b >= a.bstart[j]) e = j;
  int i = ((b - a.bstart[e]) * 256 + threadIdx.x) * 4;
  if (i >= a.total[e]) return;
  float4 v = make_float4(0.f, 0.f, 0.f, 0.f);
  if (i < a.valid[e]) v = *(const float4*)(a.src[e] + i);
  ushort4 o;
  o.x = f2b(v.x); o.y = f2b(v.y); o.z = f2b(v.z); o.w = f2b(v.w);
  *(ushort4*)(a.dst[e] + i) = o;
}

// ------------- fused l/r projection: [NPAD,256]bf16 @ [256,256]^T ----------
struct ProjArgs {
  const ushort* xb[2];
  const ushort* Wb[2];
  const float* bl[2];
  const float* br[2];
  ushort* lb[2];
  ushort* rb[2];
  int N[2];
};
__global__ __launch_bounds__(256) void proj_lr_mfma(ProjArgs g) {
  const int ty = blockIdx.z;
  const ushort* xb = g.xb[ty];
  __shared__ ushort As[128 * 32];
  __shared__ ushort Bs[128 * 32];
  const int tid = threadIdx.x;
  const int lane = tid & 63;
  const int wave = tid >> 6;
  const int wm = wave & 1, wn = wave >> 1;
  const int rowBase = blockIdx.x * 128;
  const int colHalf = blockIdx.y;
  const ushort* Wbase = g.Wb[ty] + (size_t)colHalf * 128 * 256;

  floatx4 acc[4][4] = {};

  const int srow = tid >> 2, schk = tid & 3;
  for (int k0 = 0; k0 < 256; k0 += 32) {
#pragma unroll
    for (int i = 0; i < 2; ++i) {
      gload16(xb + (size_t)(rowBase + srow + i * 64) * 256 + k0 + schk * 8,
              &As[(tid + i * 256) * 8]);
      gload16(Wbase + (size_t)(srow + i * 64) * 256 + k0 + schk * 8,
              &Bs[(tid + i * 256) * 8]);
    }
    __syncthreads();
    short8 bf[4];
#pragma unroll
    for (int nt = 0; nt < 4; ++nt)
      bf[nt] = *(const short8*)&Bs[(wn * 64 + nt * 16 + (lane & 15)) * 32 + (lane >> 4) * 8];
#pragma unroll
    for (int mt = 0; mt < 4; ++mt) {
      short8 a = *(const short8*)&As[(wm * 64 + mt * 16 + (lane & 15)) * 32 + (lane >> 4) * 8];
#pragma unroll
      for (int nt = 0; nt < 4; ++nt)
        acc[mt][nt] = __builtin_amdgcn_mfma_f32_16x16x32_bf16(a, bf[nt], acc[mt][nt], 0, 0, 0);
    }
    __syncthreads();
  }

  const int N = g.N[ty];
  const float* bias = colHalf ? g.br[ty] : g.bl[ty];
  ushort* outp = colHalf ? g.rb[ty] : g.lb[ty];
#pragma unroll
  for (int mt = 0; mt < 4; ++mt)
#pragma unroll
    for (int nt = 0; nt < 4; ++nt) {
      int col = wn * 64 + nt * 16 + (lane & 15);
      float bv = bias[col];
#pragma unroll
      for (int vi = 0; vi < 4; ++vi) {
        int row = rowBase + wm * 64 + mt * 16 + (lane >> 4) * 4 + vi;
        if (row < N) outp[(size_t)row * 128 + col] = f2b(acc[mt][nt][vi] + bv);
      }
    }
}

// ------------- batched attention projection (4 GEMMs), grid.y = entry ------
struct AttnArgs {
  const ushort* Ab[4];
  const ushort* Wb[4];
  const float* bias[4];
  float* out[4];
  int N[4];
  int BN[4];
};
__global__ __launch_bounds__(256) void attn_proj_multi(AttnArgs g) {
  const int ei = blockIdx.y;
  const ushort* Ab = g.Ab[ei];
  const ushort* Wb = g.Wb[ei];
  const int N = g.N[ei], BN = g.BN[ei];
  const int NB = BN >> 4;
  __shared__ ushort As[128 * 32];
  __shared__ ushort Ws[64 * 128];
  const int tid = threadIdx.x;
  const int lane = tid & 63;
  const int wave = tid >> 6;
  const int rowBase = blockIdx.x * 128;

  for (int i = 0; i < NB; ++i) {
    int idx = tid + i * 256;
    gload16(Wb + (size_t)idx * 8, &Ws[idx * 8]);
  }

  floatx4 acc[2][4] = {};
  for (int k0 = 0; k0 < 128; k0 += 32) {
#pragma unroll
    for (int i = 0; i < 2; ++i) {
      int t = tid + i * 256;
      gload16(Ab + (size_t)(rowBase + (t >> 2)) * 128 + k0 + (t & 3) * 8, &As[t * 8]);
    }
    __syncthreads();
    short8 bf[4];
#pragma unroll
    for (int nt = 0; nt < 4; ++nt)
      if (nt < NB)
        bf[nt] = *(const short8*)&Ws[(nt * 16 + (lane & 15)) * 128 + k0 + (lane >> 4) * 8];
#pragma unroll
    for (int mt = 0; mt < 2; ++mt) {
      short8 a = *(const short8*)&As[(wave * 32 + mt * 16 + (lane & 15)) * 32 + (lane >> 4) * 8];
#pragma unroll
      for (int nt = 0; nt < 4; ++nt)
        if (nt < NB)
          acc[mt][nt] = __builtin_amdgcn_mfma_f32_16x16x32_bf16(a, bf[nt], acc[mt][nt], 0, 0, 0);
    }
    __syncthreads();
  }
  const float* bias = g.bias[ei];
  float* out = g.out[ei];
#pragma unroll
  for (int mt = 0; mt < 2; ++mt)
#pragma unroll
    for (int nt = 0; nt < 4; ++nt) {
      if (nt >= NB) continue;
      int col = nt * 16 + (lane & 15);
      float bv = bias[col];
#pragma unroll
      for (int vi = 0; vi < 4; ++vi) {
        int row = rowBase + wave * 32 + mt * 16 + (lane >> 4) * 4 + vi;
        if (row < N) out[(size_t)row * BN + col] = acc[mt][nt][vi] + bv;
      }
    }
}

// ------- batched per-node tanh-dot (6 entries) ----------------------------
struct TanhArgs {
  const float* a[6];
  const float* q[6];
  float* out[6];
  int stride[6];
  int N[6];
  int bstart[7];
};
__global__ __launch_bounds__(256) void tanh_multi(TanhArgs t) {
  int b = blockIdx.x;
  int e = 0;
#pragma unroll
  for (int j = 1; j < 6; ++j)
    if (b >= t.bstart[j]) e = j;
  int lane32 = threadIdx.x & 31;
  int node = (b - t.bstart[e]) * 8 + (threadIdx.x >> 5);
  if (node >= t.N[e]) return;
  float p = tanhf(t.a[e][(size_t)node * t.stride[e] + lane32]) * t.q[e][lane32];
#pragma unroll
  for (int m = 16; m >= 1; m >>= 1) p += __shfl_xor(p, m, 32);
  if (lane32 == 0) t.out[e][node] = p;
}

// ------- hist + rank: deg count and per-edge rank (coalesced) -------------
__global__ __launch_bounds__(256) void hist3_kernel(
    const int* __restrict__ e0, const int* __restrict__ e1,
    const int* __restrict__ e2, int* __restrict__ deg,
    int* __restrict__ rank, int E, int NG) {
  int e = blockIdx.x * 256 + threadIdx.x;
  if (e >= 3 * E) return;
  int mp = (e >= 2 * E) ? 2 : ((e >= E) ? 1 : 0);
  int el = e - mp * E;
  const int* ep = (mp == 0) ? e0 : (mp == 1) ? e1 : e2;
  int segb = (mp == 2) ? 2 * NG : mp * NG;
  rank[e] = atomicAdd(&deg[segb + ep[el]], 1);
}

// ------- hierarchical scan: A) tile scan, B) partials, C) add prefix ------
__global__ __launch_bounds__(256) void scanA_kernel(
    const int* __restrict__ deg, int* __restrict__ offsets,
    int* __restrict__ tile_tot, int n) {
  __shared__ int wtot[4];
  const int t = threadIdx.x;
  const int base = blockIdx.x * 2048 + t * 8;
  int v[8], pre[8], s = 0;
#pragma unroll
  for (int j = 0; j < 8; ++j) {
    v[j] = (base + j < n) ? deg[base + j] : 0;
    pre[j] = s;
    s += v[j];
  }
  const int lane = t & 63, wv = t >> 6;
  int x = s;
#pragma unroll
  for (int o = 1; o < 64; o <<= 1) {
    int u = __shfl_up(x, o, 64);
    if (lane >= o) x += u;
  }
  if (lane == 63) wtot[wv] = x;
  __syncthreads();
  int wpre = 0;
#pragma unroll
  for (int j = 0; j < 4; ++j) wpre += (j < wv) ? wtot[j] : 0;
  int excl = wpre + x - s;
#pragma unroll
  for (int j = 0; j < 8; ++j)
    if (base + j < n) offsets[base + j] = excl + pre[j];
  if (t == 255) tile_tot[blockIdx.x] = wpre + x;
}

__global__ __launch_bounds__(256) void scanB_kernel(
    const int* __restrict__ tile_tot, int* __restrict__ tile_pre,
    int* __restrict__ offsets, int T, int n) {
  __shared__ int wtot[4];
  const int t = threadIdx.x;
  int v = (t < T) ? tile_tot[t] : 0;
  const int lane = t & 63, wv = t >> 6;
  int x = v;
#pragma unroll
  for (int o = 1; o < 64; o <<= 1) {
    int u = __shfl_up(x, o, 64);
    if (lane >= o) x += u;
  }
  if (lane == 63) wtot[wv] = x;
  __syncthreads();
  int wpre = 0;
#pragma unroll
  for (int j = 0; j < 4; ++j) wpre += (j < wv) ? wtot[j] : 0;
  if (t < T) tile_pre[t] = wpre + x - v;
  if (t == 255) offsets[n] = wpre + x;  // grand total
}

__global__ __launch_bounds__(256) void scanC_kernel(
    int* __restrict__ offsets, const int* __restrict__ tile_pre, int n) {
  const int add = tile_pre[blockIdx.x];
  const int base = blockIdx.x * 2048 + threadIdx.x * 8;
#pragma unroll
  for (int j = 0; j < 8; ++j)
    if (base + j < n) offsets[base + j] += add;
}

// ------- scatter3: pos = offsets[node] + rank[e]; writes {d*256, w} -------
// w = expf((tl[head]+tr[tail])*sharp) computed here, edge-parallel. The
// dst is stored pre-scaled to a row byte offset (d*256 < 2^31) so the
// gather's row address is a single u32 add.
__global__ __launch_bounds__(256) void scatter3_kernel(
    const int* __restrict__ e0, const int* __restrict__ e1,
    const int* __restrict__ e2, const int* __restrict__ rank,
    const int* __restrict__ offsets,
    const float* __restrict__ tl3, const float* __restrict__ tr3,
    const float* __restrict__ sharp, int2* __restrict__ recs,
    int E, int NG, int NP) {
  int e = blockIdx.x * 256 + threadIdx.x;
  if (e >= 3 * E) return;
  int mp = (e >= 2 * E) ? 2 : ((e >= E) ? 1 : 0);
  int el = e - mp * E;
  const int* ep = (mp == 0) ? e0 : (mp == 1) ? e1 : e2;
  int s = ep[el], d = ep[el + E];
  int hb = (mp == 2) ? 2 * NG : mp * NG;                 // head/offsets base
  int tb = (mp == 0) ? 0 : (mp == 1) ? NG : NG + NP;     // tr3 segment base
  // |tl+tr| <= sum|qw| ~ 10 -> exp safe in fp32 without max-shift.
  float w = expf((tl3[hb + s] + tr3[tb + d]) * sharp[mp]);
  recs[offsets[hb + s] + rank[e]] = make_int2(d << 8, __float_as_int(w));
}

// ------- fused gather + relation combine: wave per OUTPUT node ------------
// Quarter-wave (16 lanes x 16B uint4) per edge row: record addressing,
// clamps, selects, converts are amortized over 4 edges per wave-inst.
// Gene waves run gg+gp in one fused loop (2 edges/quarter each) so both
// relations' dependent load chains are in flight together. Clamped lanes
// read recs[j0] (in-bounds: j0a<=E, j0b<=2E < 3E) with weight forced 0.
__global__ __launch_bounds__(256) void gather_combine(
    const ushort* __restrict__ rb_gene, const ushort* __restrict__ rb_prot,
    const ushort* __restrict__ lb_gene, const ushort* __restrict__ lb_prot,
    const int* __restrict__ offsets, const int2* __restrict__ recs,
    const float* __restrict__ cgW, const float* __restrict__ cgb,
    const float* __restrict__ cpW, const float* __restrict__ cpb,
    float* __restrict__ out_gene, float* __restrict__ out_prot,
    int NG, int NP) {
  const int lane = threadIdx.x & 63;
  const int q = lane >> 4;                 // quarter 0..3
  const int l16 = lane & 15;
  const int node = blockIdx.x * 4 + (threadIdx.x >> 6);
  if (node >= NG + NP) return;
  const bool isGene = node < NG;
  const unsigned coloff = (unsigned)l16 << 4;   // 16 B per lane

  const int h0 = isGene ? node : NG + node;     // gg for genes / pp for prots
  const int j0a = offsets[h0];
  const int ca = offsets[h0 + 1] - j0a;
  int j0b = 0, cb2 = 0;
  if (isGene) {
    j0b = offsets[NG + node];
    cb2 = offsets[NG + node + 1] - j0b;
  }

  float a0[8] = {0.f, 0.f, 0.f, 0.f, 0.f, 0.f, 0.f, 0.f};
  float a1[8] = {0.f, 0.f, 0.f, 0.f, 0.f, 0.f, 0.f, 0.f};
  float ds0 = 0.f, ds1 = 0.f;
  const ushort* rtA = isGene ? rb_gene : rb_prot;

  if (isGene) {
    const int cmax = (ca > cb2) ? ca : cb2;
    const int nit = (cmax + 7) >> 3;            // 8 edges per relation/iter
    for (int it = 0; it < nit; ++it) {
      const int b = it * 8 + q * 2;
      int2 rA[2], rB[2];
#pragma unroll
      for (int p = 0; p < 2; ++p) {
        const int i = b + p;
        rA[p] = recs[j0a + ((i < ca) ? i : 0)];
        rB[p] = recs[j0b + ((i < cb2) ? i : 0)];
      }
      float wA[2], wB[2];
      uint4 vA[2], vB[2];
#pragma unroll
      for (int p = 0; p < 2; ++p) {
        const int i = b + p;
        wA[p] = (i < ca) ? __int_as_float(rA[p].y) : 0.f;
        wB[p] = (i < cb2) ? __int_as_float(rB[p].y) : 0.f;
        vA[p] = *(const uint4*)((const char*)rtA + ((unsigned)rA[p].x + coloff));
        vB[p] = *(const uint4*)((const char*)rb_prot + ((unsigned)rB[p].x + coloff));
      }
#pragma unroll
      for (int p = 0; p < 2; ++p) {
        ds0 += wA[p];
        a0[0] += b2f_lo(vA[p].x) * wA[p]; a0[1] += b2f_hi(vA[p].x) * wA[p];
        a0[2] += b2f_lo(vA[p].y) * wA[p]; a0[3] += b2f_hi(vA[p].y) * wA[p];
        a0[4] += b2f_lo(vA[p].z) * wA[p]; a0[5] += b2f_hi(vA[p].z) * wA[p];
        a0[6] += b2f_lo(vA[p].w) * wA[p]; a0[7] += b2f_hi(vA[p].w) * wA[p];
        ds1 += wB[p];
        a1[0] += b2f_lo(vB[p].x) * wB[p]; a1[1] += b2f_hi(vB[p].x) * wB[p];
        a1[2] += b2f_lo(vB[p].y) * wB[p]; a1[3] += b2f_hi(vB[p].y) * wB[p];
        a1[4] += b2f_lo(vB[p].z) * wB[p]; a1[5] += b2f_hi(vB[p].z) * wB[p];
        a1[6] += b2f_lo(vB[p].w) * wB[p]; a1[7] += b2f_hi(vB[p].w) * wB[p];
      }
    }
  } else {
    const int nit = (ca + 15) >> 4;             // 16 edges per iter
    for (int it = 0; it < nit; ++it) {
      const int b = it * 16 + q * 4;
      int2 rc[4];
#pragma unroll
      for (int p = 0; p < 4; ++p) {
        const int i = b + p;
        rc[p] = recs[j0a + ((i < ca) ? i : 0)];
      }
      float w[4];
      uint4 v[4];
#pragma unroll
      for (int p = 0; p < 4; ++p) {
        const int i = b + p;
        w[p] = (i < ca) ? __int_as_float(rc[p].y) : 0.f;
        v[p] = *(const uint4*)((const char*)rtA + ((unsigned)rc[p].x + coloff));
      }
#pragma unroll
      for (int p = 0; p < 4; ++p) {
        ds0 += w[p];
        a0[0] += b2f_lo(v[p].x) * w[p]; a0[1] += b2f_hi(v[p].x) * w[p];
        a0[2] += b2f_lo(v[p].y) * w[p]; a0[3] += b2f_hi(v[p].y) * w[p];
        a0[4] += b2f_lo(v[p].z) * w[p]; a0[5] += b2f_hi(v[p].z) * w[p];
        a0[6] += b2f_lo(v[p].w) * w[p]; a0[7] += b2f_hi(v[p].w) * w[p];
      }
    }
  }

  // fold quarters: each quarter covered the FULL 128-col row for its edge
  // subset -> sum over quarters via xor-16 + xor-32.
#pragma unroll
  for (int c = 0; c < 8; ++c) {
    a0[c] += __shfl_xor(a0[c], 16, 64);
    a0[c] += __shfl_xor(a0[c], 32, 64);
  }
  ds0 += __shfl_xor(ds0, 16, 64);
  ds0 += __shfl_xor(ds0, 32, 64);
  if (isGene) {
#pragma unroll
    for (int c = 0; c < 8; ++c) {
      a1[c] += __shfl_xor(a1[c], 16, 64);
      a1[c] += __shfl_xor(a1[c], 32, 64);
    }
    ds1 += __shfl_xor(ds1, 16, 64);
    ds1 += __shfl_xor(ds1, 32, 64);
  }

  const float inv0 = 1.f / (ds0 + 1e-16f);
  const float inv1 = 1.f / (ds1 + 1e-16f);
  float g0[8], g1[8], self[8];
#pragma unroll
  for (int c = 0; c < 8; ++c) { g0[c] = a0[c] * inv0; g1[c] = a1[c] * inv1; }
  {
    const ushort* lbp = isGene ? lb_gene + (size_t)node * 128
                               : lb_prot + (size_t)(node - NG) * 128;
    uint4 sv = *(const uint4*)(lbp + l16 * 8);
    self[0] = b2f_lo(sv.x); self[1] = b2f_hi(sv.x);
    self[2] = b2f_lo(sv.y); self[3] = b2f_hi(sv.y);
    self[4] = b2f_lo(sv.z); self[5] = b2f_hi(sv.z);
    self[6] = b2f_lo(sv.w); self[7] = b2f_hi(sv.w);
  }

  const float* cW = isGene ? cgW : cpW;
  const float cb = isGene ? cgb[0] : cpb[0];
  const float4 wlo = *(const float4*)(cW + l16 * 8);
  const float4 whi = *(const float4*)(cW + l16 * 8 + 4);
  float p0 = g0[0] * wlo.x + g0[1] * wlo.y + g0[2] * wlo.z + g0[3] * wlo.w +
             g0[4] * whi.x + g0[5] * whi.y + g0[6] * whi.z + g0[7] * whi.w;
  float p1 = g1[0] * wlo.x + g1[1] * wlo.y + g1[2] * wlo.z + g1[3] * wlo.w +
             g1[4] * whi.x + g1[5] * whi.y + g1[6] * whi.z + g1[7] * whi.w;
  float ps = self[0] * wlo.x + self[1] * wlo.y + self[2] * wlo.z + self[3] * wlo.w +
             self[4] * whi.x + self[5] * whi.y + self[6] * whi.z + self[7] * whi.w;
#pragma unroll
  for (int m = 8; m >= 1; m >>= 1) {  // reduce the 16 col-lanes (quarters dup)
    p0 += __shfl_xor(p0, m, 64);
    p1 += __shfl_xor(p1, m, 64);
    ps += __shfl_xor(ps, m, 64);
  }
  const float s0 = p0 + cb, s1 = p1 + cb, ss = ps + cb;
  const float mx = isGene ? fmaxf(fmaxf(s0, s1), ss) : fmaxf(s0, ss);
  const float e0 = expf(s0 - mx);
  const float e1 = isGene ? expf(s1 - mx) : 0.f;
  const float es = expf(ss - mx);
  const float sum = e0 + e1 + es;
  const float b0 = e0 / sum, b1 = e1 / sum, bs = es / sum;

  if (q == 0) {
    float4 o0, o1;
    o0.x = fmaxf(g0[0] * b0 + g1[0] * b1 + self[0] * bs, 0.f);
    o0.y = fmaxf(g0[1] * b0 + g1[1] * b1 + self[1] * bs, 0.f);
    o0.z = fmaxf(g0[2] * b0 + g1[2] * b1 + self[2] * bs, 0.f);
    o0.w = fmaxf(g0[3] * b0 + g1[3] * b1 + self[3] * bs, 0.f);
    o1.x = fmaxf(g0[4] * b0 + g1[4] * b1 + self[4] * bs, 0.f);
    o1.y = fmaxf(g0[5] * b0 + g1[5] * b1 + self[5] * bs, 0.f);
    o1.z = fmaxf(g0[6] * b0 + g1[6] * b1 + self[6] * bs, 0.f);
    o1.w = fmaxf(g0[7] * b0 + g1[7] * b1 + self[7] * bs, 0.f);
    float* op = isGene ? out_gene + (size_t)node * 128
                       : out_prot + (size_t)(node - NG) * 128;
    *(float4*)(op + l16 * 8) = o0;
    *(float4*)(op + l16 * 8 + 4) = o1;
  }
}

// ---------------------------------------------------------------------------
extern "C" void kernel_launch(void* const* d_in, const int* in_sizes, int n_in,
                              void* d_out, int out_size, void* d_ws,
                              size_t ws_size, hipStream_t stream) {
  const float* x_gene  = (const float*)d_in[0];
  const float* x_prot  = (const float*)d_in[1];
  const float* Wl_gene = (const float*)d_in[2];
  const float* bl_gene = (const float*)d_in[3];
  const float* Wr_gene = (const float*)d_in[4];
  const float* br_gene = (const float*)d_in[5];
  const float* Wl_prot = (const float*)d_in[6];
  const float* bl_prot = (const float*)d_in[7];
  const float* Wr_prot = (const float*)d_in[8];
  const float* br_prot = (const float*)d_in[9];
  const float* alW     = (const float*)d_in[10];  // [3,32,128] contiguous
  const float* alb     = (const float*)d_in[11];  // [3,32] contiguous
  const float* arW     = (const float*)d_in[12];
  const float* arb     = (const float*)d_in[13];
  const float* qw      = (const float*)d_in[14];  // [3,64,1]
  const float* sharp   = (const float*)d_in[15];
  const float* cgW     = (const float*)d_in[16];
  const float* cgb     = (const float*)d_in[17];
  const float* cpW     = (const float*)d_in[18];
  const float* cpb     = (const float*)d_in[19];
  const int* e_gg      = (const int*)d_in[20];
  const int* e_gp      = (const int*)d_in[21];
  const int* e_pp      = (const int*)d_in[22];

  const int NG = in_sizes[0] / 256;
  const int NP = in_sizes[1] / 256;
  const int E  = in_sizes[20] / 2;
  const int NPG = (NG + 127) & ~127;
  const int NPP = (NP + 127) & ~127;
  const int NT = 2 * NG + NP;          // concatenated head-node space
  const int NR = NG + 2 * NP;          // concatenated tail-node space (tr)

  char* base = (char*)d_ws;
  size_t off = 0;
  auto alloc = [&](size_t bytes) {
    void* p = base + off;
    off = (off + bytes + 255) & ~(size_t)255;
    return p;
  };
  ushort* xb_gene = (ushort*)alloc((size_t)NPG * 256 * 2);
  ushort* xb_prot = (ushort*)alloc((size_t)NPP * 256 * 2);
  // aliases over xb region (valid after proj phase; 96*4=384 < 512 B/row)
  float* al_gene = (float*)xb_gene;                 // [NPG,64] = al0|al1
  float* ar_gene = al_gene + (size_t)NPG * 64;      // [NPG,32]
  float* al_prot = ar_gene + (size_t)NPG * 32;      // [NPP,32]
  float* ar_prot = al_prot + (size_t)NPP * 32;      // [NPP,64] = ar1|ar2

  ushort* Wlr_gene = (ushort*)alloc(256 * 256 * 2);
  ushort* Wlr_prot = (ushort*)alloc(256 * 256 * 2);
  ushort* alWb     = (ushort*)alloc(96 * 128 * 2);
  ushort* arWb     = (ushort*)alloc(96 * 128 * 2);
  ushort* lb_gene  = (ushort*)alloc((size_t)NPG * 128 * 2);
  ushort* rb_gene  = (ushort*)alloc((size_t)NPG * 128 * 2);
  ushort* lb_prot  = (ushort*)alloc((size_t)NPP * 128 * 2);
  ushort* rb_prot  = (ushort*)alloc((size_t)NPP * 128 * 2);
  int*    deg      = (int*)alloc((size_t)NT * 4);
  int*    offsets  = (int*)alloc((size_t)(NT + 1) * 4);
  const int TILES  = (NT + 2047) / 2048;
  int*    tile_tot = (int*)alloc((size_t)TILES * 4);
  int*    tile_pre = (int*)alloc((size_t)TILES * 4);
  int*    rank     = (int*)alloc((size_t)(3 * E) * 4);
  int2*   recs     = (int2*)alloc((size_t)(3 * E) * sizeof(int2));
  float*  tl3      = (float*)alloc((size_t)NT * 4);
  float*  tr3      = (float*)alloc((size_t)NR * 4);

  float* out_gene = (float*)d_out;
  float* out_prot = out_gene + (size_t)NG * 128;

  dim3 blk(256);

  // ---- 0) batched bf16 conversions (1 dispatch) ----
  {
    CvtArgs a;
    const float* srcs[8] = {x_gene, x_prot, Wl_gene, Wr_gene, Wl_prot, Wr_prot, alW, arW};
    ushort* dsts[8] = {xb_gene, xb_prot, Wlr_gene, Wlr_gene + 128 * 256,
                       Wlr_prot, Wlr_prot + 128 * 256, alWb, arWb};
    int valids[8] = {NG * 256, NP * 256, 128 * 256, 128 * 256, 128 * 256, 128 * 256, 96 * 128, 96 * 128};
    int totals[8] = {NPG * 256, NPP * 256, 128 * 256, 128 * 256, 128 * 256, 128 * 256, 96 * 128, 96 * 128};
    int b = 0;
    for (int j = 0; j < 8; ++j) {
      a.src[j] = srcs[j]; a.dst[j] = dsts[j];
      a.valid[j] = valids[j]; a.total[j] = totals[j];
      a.bstart[j] = b;
      b += (totals[j] / 4 + 255) / 256;
    }
    a.bstart[8] = b;
    cvt_multi<<<b, blk, 0, stream>>>(a);
  }

  // ---- 1) fused l/r projections, both node types (1 dispatch) ----
  {
    ProjArgs p;
    p.xb[0] = xb_gene; p.xb[1] = xb_prot;
    p.Wb[0] = Wlr_gene; p.Wb[1] = Wlr_prot;
    p.bl[0] = bl_gene; p.bl[1] = bl_prot;
    p.br[0] = br_gene; p.br[1] = br_prot;
    p.lb[0] = lb_gene; p.lb[1] = lb_prot;
    p.rb[0] = rb_gene; p.rb[1] = rb_prot;
    p.N[0] = NG; p.N[1] = NP;
    proj_lr_mfma<<<dim3(NPG / 128, 2, 2), blk, 0, stream>>>(p);
  }

  // ---- 2) batched attention projections (1 dispatch) ----
  {
    AttnArgs a;
    a.Ab[0] = lb_gene; a.Wb[0] = alWb;            a.bias[0] = alb;      a.out[0] = al_gene; a.N[0] = NG; a.BN[0] = 64;
    a.Ab[1] = rb_gene; a.Wb[1] = arWb;            a.bias[1] = arb;      a.out[1] = ar_gene; a.N[1] = NG; a.BN[1] = 32;
    a.Ab[2] = lb_prot; a.Wb[2] = alWb + 64 * 128; a.bias[2] = alb + 64; a.out[2] = al_prot; a.N[2] = NP; a.BN[2] = 32;
    a.Ab[3] = rb_prot; a.Wb[3] = arWb + 32 * 128; a.bias[3] = arb + 32; a.out[3] = ar_prot; a.N[3] = NP; a.BN[3] = 64;
    attn_proj_multi<<<dim3(NPG / 128, 4), blk, 0, stream>>>(a);
  }

  // ---- 3) batched per-node tanh-dot scalars (1 dispatch) ----
  {
    TanhArgs t;
    const float* as[6] = {al_gene, ar_gene, al_gene + 32, ar_prot, al_prot, ar_prot + 32};
    const float* qs[6] = {qw + 0, qw + 32, qw + 64, qw + 96, qw + 128, qw + 160};
    float* outs[6] = {tl3, tr3, tl3 + NG, tr3 + NG, tl3 + 2 * NG, tr3 + NG + NP};
    int strides[6] = {64, 32, 64, 64, 32, 64};
    int Ns[6] = {NG, NG, NG, NP, NP, NP};
    int b = 0;
    for (int j = 0; j < 6; ++j) {
      t.a[j] = as[j]; t.q[j] = qs[j]; t.out[j] = outs[j];
      t.stride[j] = strides[j]; t.N[j] = Ns[j];
      t.bstart[j] = b;
      b += (Ns[j] + 7) / 8;
    }
    t.bstart[6] = b;
    tanh_multi<<<b, blk, 0, stream>>>(t);
  }

  // ---- 4) CSR build (hist+rank -> scan -> scatter{d*256,w}) ----
  const int gridE3 = (3 * E + 255) / 256;
  hipMemsetAsync(deg, 0, (size_t)NT * sizeof(int), stream);
  hist3_kernel<<<gridE3, blk, 0, stream>>>(e_gg, e_gp, e_pp, deg, rank, E, NG);
  scanA_kernel<<<TILES, blk, 0, stream>>>(deg, offsets, tile_tot, NT);
  scanB_kernel<<<1, blk, 0, stream>>>(tile_tot, tile_pre, offsets, TILES, NT);
  scanC_kernel<<<TILES, blk, 0, stream>>>(offsets, tile_pre, NT);
  scatter3_kernel<<<gridE3, blk, 0, stream>>>(e_gg, e_gp, e_pp, rank, offsets,
                                              tl3, tr3, sharp, recs, E, NG, NP);

  // ---- 5) fused gather + relation combine (1 dispatch) ----
  gather_combine<<<(NG + NP + 3) / 4, blk, 0, stream>>>(
      rb_gene, rb_prot, lb_gene, lb_prot, offsets, recs,
      cgW, cgb, cpW, cpb, out_gene, out_prot, NG, NP);
}

// Round 4
// 429.756 us; speedup vs baseline: 1.0851x; 1.0723x over previous
//
#include <hip/hip_runtime.h>
#include <hip/hip_bf16.h>

// ---------------------------------------------------------------------------
// LATTE heterogeneous GNN layer (gene/protein).
// R12: (a) gather_combine goes QUARTER-PER-NODE: each 16-lane quarter owns
//      one output node (4 nodes/wave). Epilogue (normalize/dot/softmax/store)
//      is amortized 4x; ds needs NO reduce (lane-uniform in quarter); beta
//      dot reduce is 4 xor steps. (b) record-PREFETCH pipeline: iteration
//      it+1's records load before it's FMAs -> one latency epoch/iter, not
//      two. (c) tanh_multi is FUSED into attn_proj's epilogue: tl3/tr3 are
//      computed straight from MFMA accumulators (intra-16-lane reduce); the
//      al/ar intermediates (76 MB traffic) and one dispatch are gone.
// ---------------------------------------------------------------------------

typedef __attribute__((ext_vector_type(8))) short short8;   // 8 bf16
typedef __attribute__((ext_vector_type(4))) float floatx4;  // 4 f32 acc

__device__ __forceinline__ void gload16(const void* g, void* l) {
  __builtin_amdgcn_global_load_lds(
      (const __attribute__((address_space(1))) void*)g,
      (__attribute__((address_space(3))) void*)l, 16, 0, 0);
}

__device__ __forceinline__ ushort f2b(float x) {
  __hip_bfloat16 h = __float2bfloat16(x);
  return *reinterpret_cast<ushort*>(&h);
}
__device__ __forceinline__ float b2f_lo(unsigned v) { return __uint_as_float(v << 16); }
__device__ __forceinline__ float b2f_hi(unsigned v) { return __uint_as_float(v & 0xffff0000u); }

// ---------------- batched fp32 -> bf16 convert (8 tensors) -----------------
struct CvtArgs {
  const float* src[8];
  ushort* dst[8];
  int valid[8];
  int total[8];
  int bstart[9];
};
__global__ __launch_bounds__(256) void cvt_multi(CvtArgs a) {
  int b = blockIdx.x;
  int e = 0;
#pragma unroll
  for (int j = 1; j < 8; ++j)
    if (b >= a.bstart[j]) e = j;
  int i = ((b - a.bstart[e]) * 256 + threadIdx.x) * 4;
  if (i >= a.total[e]) return;
  float4 v = make_float4(0.f, 0.f, 0.f, 0.f);
  if (i < a.valid[e]) v = *(const float4*)(a.src[e] + i);
  ushort4 o;
  o.x = f2b(v.x); o.y = f2b(v.y); o.z = f2b(v.z); o.w = f2b(v.w);
  *(ushort4*)(a.dst[e] + i) = o;
}

// ------------- fused l/r projection: [NPAD,256]bf16 @ [256,256]^T ----------
struct ProjArgs {
  const ushort* xb[2];
  const ushort* Wb[2];
  const float* bl[2];
  const float* br[2];
  ushort* lb[2];
  ushort* rb[2];
  int N[2];
};
__global__ __launch_bounds__(256) void proj_lr_mfma(ProjArgs g) {
  const int ty = blockIdx.z;
  const ushort* xb = g.xb[ty];
  __shared__ ushort As[128 * 32];
  __shared__ ushort Bs[128 * 32];
  const int tid = threadIdx.x;
  const int lane = tid & 63;
  const int wave = tid >> 6;
  const int wm = wave & 1, wn = wave >> 1;
  const int rowBase = blockIdx.x * 128;
  const int colHalf = blockIdx.y;
  const ushort* Wbase = g.Wb[ty] + (size_t)colHalf * 128 * 256;

  floatx4 acc[4][4] = {};

  const int srow = tid >> 2, schk = tid & 3;
  for (int k0 = 0; k0 < 256; k0 += 32) {
#pragma unroll
    for (int i = 0; i < 2; ++i) {
      gload16(xb + (size_t)(rowBase + srow + i * 64) * 256 + k0 + schk * 8,
              &As[(tid + i * 256) * 8]);
      gload16(Wbase + (size_t)(srow + i * 64) * 256 + k0 + schk * 8,
              &Bs[(tid + i * 256) * 8]);
    }
    __syncthreads();
    short8 bf[4];
#pragma unroll
    for (int nt = 0; nt < 4; ++nt)
      bf[nt] = *(const short8*)&Bs[(wn * 64 + nt * 16 + (lane & 15)) * 32 + (lane >> 4) * 8];
#pragma unroll
    for (int mt = 0; mt < 4; ++mt) {
      short8 a = *(const short8*)&As[(wm * 64 + mt * 16 + (lane & 15)) * 32 + (lane >> 4) * 8];
#pragma unroll
      for (int nt = 0; nt < 4; ++nt)
        acc[mt][nt] = __builtin_amdgcn_mfma_f32_16x16x32_bf16(a, bf[nt], acc[mt][nt], 0, 0, 0);
    }
    __syncthreads();
  }

  const int N = g.N[ty];
  const float* bias = colHalf ? g.br[ty] : g.bl[ty];
  ushort* outp = colHalf ? g.rb[ty] : g.lb[ty];
#pragma unroll
  for (int mt = 0; mt < 4; ++mt)
#pragma unroll
    for (int nt = 0; nt < 4; ++nt) {
      int col = wn * 64 + nt * 16 + (lane & 15);
      float bv = bias[col];
#pragma unroll
      for (int vi = 0; vi < 4; ++vi) {
        int row = rowBase + wm * 64 + mt * 16 + (lane >> 4) * 4 + vi;
        if (row < N) outp[(size_t)row * 128 + col] = f2b(acc[mt][nt][vi] + bv);
      }
    }
}

// ------------- batched attention projection + FUSED tanh-dot ---------------
// Computes acc = Ab @ Wb^T (+bias), then directly reduces
// tl/tr[row] = sum_col tanh(acc[row,col]+bias[col]) * q[col] over 32-col
// halves. al/ar are never materialized.
struct AttnArgs {
  const ushort* Ab[4];
  const ushort* Wb[4];
  const float* bias[4];
  const float* q0[4];   // cols 0..31
  const float* q1[4];   // cols 32..63 (entries with BN=64)
  float* o0[4];
  float* o1[4];
  int N[4];
  int BN[4];
};
__global__ __launch_bounds__(256) void attn_proj_multi(AttnArgs g) {
  const int ei = blockIdx.y;
  const ushort* Ab = g.Ab[ei];
  const ushort* Wb = g.Wb[ei];
  const int N = g.N[ei], BN = g.BN[ei];
  const int NB = BN >> 4;
  __shared__ ushort As[128 * 32];
  __shared__ ushort Ws[64 * 128];
  const int tid = threadIdx.x;
  const int lane = tid & 63;
  const int wave = tid >> 6;
  const int rowBase = blockIdx.x * 128;

  for (int i = 0; i < NB; ++i) {
    int idx = tid + i * 256;
    gload16(Wb + (size_t)idx * 8, &Ws[idx * 8]);
  }

  floatx4 acc[2][4] = {};
  for (int k0 = 0; k0 < 128; k0 += 32) {
#pragma unroll
    for (int i = 0; i < 2; ++i) {
      int t = tid + i * 256;
      gload16(Ab + (size_t)(rowBase + (t >> 2)) * 128 + k0 + (t & 3) * 8, &As[t * 8]);
    }
    __syncthreads();
    short8 bf[4];
#pragma unroll
    for (int nt = 0; nt < 4; ++nt)
      if (nt < NB)
        bf[nt] = *(const short8*)&Ws[(nt * 16 + (lane & 15)) * 128 + k0 + (lane >> 4) * 8];
#pragma unroll
    for (int mt = 0; mt < 2; ++mt) {
      short8 a = *(const short8*)&As[(wave * 32 + mt * 16 + (lane & 15)) * 32 + (lane >> 4) * 8];
#pragma unroll
      for (int nt = 0; nt < 4; ++nt)
        if (nt < NB)
          acc[mt][nt] = __builtin_amdgcn_mfma_f32_16x16x32_bf16(a, bf[nt], acc[mt][nt], 0, 0, 0);
    }
    __syncthreads();
  }

  // ---- fused epilogue: tanh-dot reduce into per-row scalars ----
  const float* bias = g.bias[ei];
  const int l15 = lane & 15;
  const bool two = (NB == 4);
  float bv[4];
#pragma unroll
  for (int nt = 0; nt < 4; ++nt) bv[nt] = (nt < NB) ? bias[nt * 16 + l15] : 0.f;
  float q0v0 = g.q0[ei][l15], q0v1 = g.q0[ei][16 + l15];
  float q1v0 = 0.f, q1v1 = 0.f;
  if (two) { q1v0 = g.q1[ei][l15]; q1v1 = g.q1[ei][16 + l15]; }
  float* o0 = g.o0[ei];
  float* o1 = g.o1[ei];
#pragma unroll
  for (int mt = 0; mt < 2; ++mt)
#pragma unroll
    for (int vi = 0; vi < 4; ++vi) {
      float slo = tanhf(acc[mt][0][vi] + bv[0]) * q0v0
                + tanhf(acc[mt][1][vi] + bv[1]) * q0v1;
      float shi = 0.f;
      if (two)
        shi = tanhf(acc[mt][2][vi] + bv[2]) * q1v0
            + tanhf(acc[mt][3][vi] + bv[3]) * q1v1;
#pragma unroll
      for (int m = 8; m >= 1; m >>= 1) {
        slo += __shfl_xor(slo, m, 64);   // xor<16 stays in the 16-lane group
        shi += __shfl_xor(shi, m, 64);
      }
      const int row = rowBase + wave * 32 + mt * 16 + (lane >> 4) * 4 + vi;
      if (l15 == 0 && row < N) {
        o0[row] = slo;
        if (two) o1[row] = shi;
      }
    }
}

// ------- hist + rank: deg count and per-edge rank (coalesced) -------------
__global__ __launch_bounds__(256) void hist3_kernel(
    const int* __restrict__ e0, const int* __restrict__ e1,
    const int* __restrict__ e2, int* __restrict__ deg,
    int* __restrict__ rank, int E, int NG) {
  int e = blockIdx.x * 256 + threadIdx.x;
  if (e >= 3 * E) return;
  int mp = (e >= 2 * E) ? 2 : ((e >= E) ? 1 : 0);
  int el = e - mp * E;
  const int* ep = (mp == 0) ? e0 : (mp == 1) ? e1 : e2;
  int segb = (mp == 2) ? 2 * NG : mp * NG;
  rank[e] = atomicAdd(&deg[segb + ep[el]], 1);
}

// ------- hierarchical scan: A) tile scan, B) partials, C) add prefix ------
__global__ __launch_bounds__(256) void scanA_kernel(
    const int* __restrict__ deg, int* __restrict__ offsets,
    int* __restrict__ tile_tot, int n) {
  __shared__ int wtot[4];
  const int t = threadIdx.x;
  const int base = blockIdx.x * 2048 + t * 8;
  int v[8], pre[8], s = 0;
#pragma unroll
  for (int j = 0; j < 8; ++j) {
    v[j] = (base + j < n) ? deg[base + j] : 0;
    pre[j] = s;
    s += v[j];
  }
  const int lane = t & 63, wv = t >> 6;
  int x = s;
#pragma unroll
  for (int o = 1; o < 64; o <<= 1) {
    int u = __shfl_up(x, o, 64);
    if (lane >= o) x += u;
  }
  if (lane == 63) wtot[wv] = x;
  __syncthreads();
  int wpre = 0;
#pragma unroll
  for (int j = 0; j < 4; ++j) wpre += (j < wv) ? wtot[j] : 0;
  int excl = wpre + x - s;
#pragma unroll
  for (int j = 0; j < 8; ++j)
    if (base + j < n) offsets[base + j] = excl + pre[j];
  if (t == 255) tile_tot[blockIdx.x] = wpre + x;
}

__global__ __launch_bounds__(256) void scanB_kernel(
    const int* __restrict__ tile_tot, int* __restrict__ tile_pre,
    int* __restrict__ offsets, int T, int n) {
  __shared__ int wtot[4];
  const int t = threadIdx.x;
  int v = (t < T) ? tile_tot[t] : 0;
  const int lane = t & 63, wv = t >> 6;
  int x = v;
#pragma unroll
  for (int o = 1; o < 64; o <<= 1) {
    int u = __shfl_up(x, o, 64);
    if (lane >= o) x += u;
  }
  if (lane == 63) wtot[wv] = x;
  __syncthreads();
  int wpre = 0;
#pragma unroll
  for (int j = 0; j < 4; ++j) wpre += (j < wv) ? wtot[j] : 0;
  if (t < T) tile_pre[t] = wpre + x - v;
  if (t == 255) offsets[n] = wpre + x;  // grand total
}

__global__ __launch_bounds__(256) void scanC_kernel(
    int* __restrict__ offsets, const int* __restrict__ tile_pre, int n) {
  const int add = tile_pre[blockIdx.x];
  const int base = blockIdx.x * 2048 + threadIdx.x * 8;
#pragma unroll
  for (int j = 0; j < 8; ++j)
    if (base + j < n) offsets[base + j] += add;
}

// ------- scatter3: pos = offsets[node] + rank[e]; writes {d*256, w} -------
__global__ __launch_bounds__(256) void scatter3_kernel(
    const int* __restrict__ e0, const int* __restrict__ e1,
    const int* __restrict__ e2, const int* __restrict__ rank,
    const int* __restrict__ offsets,
    const float* __restrict__ tl3, const float* __restrict__ tr3,
    const float* __restrict__ sharp, int2* __restrict__ recs,
    int E, int NG, int NP) {
  int e = blockIdx.x * 256 + threadIdx.x;
  if (e >= 3 * E) return;
  int mp = (e >= 2 * E) ? 2 : ((e >= E) ? 1 : 0);
  int el = e - mp * E;
  const int* ep = (mp == 0) ? e0 : (mp == 1) ? e1 : e2;
  int s = ep[el], d = ep[el + E];
  int hb = (mp == 2) ? 2 * NG : mp * NG;                 // head/offsets base
  int tb = (mp == 0) ? 0 : (mp == 1) ? NG : NG + NP;     // tr3 segment base
  // |tl+tr| <= sum|qw| ~ 10 -> exp safe in fp32 without max-shift.
  float w = expf((tl3[hb + s] + tr3[tb + d]) * sharp[mp]);
  recs[offsets[hb + s] + rank[e]] = make_int2(d << 8, __float_as_int(w));
}

// ------- fused gather + relation combine: QUARTER per OUTPUT node ---------
// Each 16-lane quarter owns one node (4 nodes/wave): lane covers 16 B of the
// 256-B row, records are quarter-uniform (ds needs no reduce), epilogue is
// shared across 4 nodes. Records for iter it+1 are prefetched before it's
// FMAs -> one latency epoch per iteration. Clamped lanes re-read index j0
// (weight forced 0); row offsets masked to stay in-workspace.
__global__ __launch_bounds__(256) void gather_combine(
    const ushort* __restrict__ rb_gene, const ushort* __restrict__ rb_prot,
    const ushort* __restrict__ lb_gene, const ushort* __restrict__ lb_prot,
    const int* __restrict__ offsets, const int2* __restrict__ recs,
    const float* __restrict__ cgW, const float* __restrict__ cgb,
    const float* __restrict__ cpW, const float* __restrict__ cpb,
    float* __restrict__ out_gene, float* __restrict__ out_prot,
    int NG, int NP) {
  const int lane = threadIdx.x & 63;
  const int l16 = lane & 15;
  const int node = blockIdx.x * 16 + (threadIdx.x >> 4);
  if (node >= NG + NP) return;
  const bool isGene = node < NG;
  const unsigned coloff = (unsigned)l16 << 4;   // 16 B per lane
  const unsigned OMASK = 0x00FFFF00u;           // bounds stray row offsets

  const int h0 = isGene ? node : NG + node;     // gg for genes / pp for prots
  const int j0a = offsets[h0];
  const int ca = offsets[h0 + 1] - j0a;
  int j0b = 0, cb2 = 0;
  if (isGene) {
    j0b = offsets[NG + node];
    cb2 = offsets[NG + node + 1] - j0b;
  }

  float a0[8] = {0.f, 0.f, 0.f, 0.f, 0.f, 0.f, 0.f, 0.f};
  float a1[8] = {0.f, 0.f, 0.f, 0.f, 0.f, 0.f, 0.f, 0.f};
  float ds0 = 0.f, ds1 = 0.f;
  const ushort* rtA = isGene ? rb_gene : rb_prot;

  if (isGene) {
    const int cmax = (ca > cb2) ? ca : cb2;
    if (cmax > 0) {
      // prefetch records for iteration 0 (2 per relation)
      int2 rA0 = recs[j0a];
      int2 rA1 = recs[j0a + ((1 < ca) ? 1 : 0)];
      int2 rB0 = recs[j0b];
      int2 rB1 = recs[j0b + ((1 < cb2) ? 1 : 0)];
      const int nit = (cmax + 1) >> 1;
      for (int it = 0; it < nit; ++it) {
        const int b = it * 2;
        const float wA0 = (b < ca)      ? __int_as_float(rA0.y) : 0.f;
        const float wA1 = (b + 1 < ca)  ? __int_as_float(rA1.y) : 0.f;
        const float wB0 = (b < cb2)     ? __int_as_float(rB0.y) : 0.f;
        const float wB1 = (b + 1 < cb2) ? __int_as_float(rB1.y) : 0.f;
        const uint4 vA0 = *(const uint4*)((const char*)rtA + (((unsigned)rA0.x & OMASK) + coloff));
        const uint4 vA1 = *(const uint4*)((const char*)rtA + (((unsigned)rA1.x & OMASK) + coloff));
        const uint4 vB0 = *(const uint4*)((const char*)rb_prot + (((unsigned)rB0.x & OMASK) + coloff));
        const uint4 vB1 = *(const uint4*)((const char*)rb_prot + (((unsigned)rB1.x & OMASK) + coloff));
        // prefetch next iteration's records while rows are in flight
        const int nb = b + 2;
        rA0 = recs[j0a + ((nb < ca) ? nb : 0)];
        rA1 = recs[j0a + ((nb + 1 < ca) ? nb + 1 : 0)];
        rB0 = recs[j0b + ((nb < cb2) ? nb : 0)];
        rB1 = recs[j0b + ((nb + 1 < cb2) ? nb + 1 : 0)];
        ds0 += wA0 + wA1;
        a0[0] += b2f_lo(vA0.x) * wA0 + b2f_lo(vA1.x) * wA1;
        a0[1] += b2f_hi(vA0.x) * wA0 + b2f_hi(vA1.x) * wA1;
        a0[2] += b2f_lo(vA0.y) * wA0 + b2f_lo(vA1.y) * wA1;
        a0[3] += b2f_hi(vA0.y) * wA0 + b2f_hi(vA1.y) * wA1;
        a0[4] += b2f_lo(vA0.z) * wA0 + b2f_lo(vA1.z) * wA1;
        a0[5] += b2f_hi(vA0.z) * wA0 + b2f_hi(vA1.z) * wA1;
        a0[6] += b2f_lo(vA0.w) * wA0 + b2f_lo(vA1.w) * wA1;
        a0[7] += b2f_hi(vA0.w) * wA0 + b2f_hi(vA1.w) * wA1;
        ds1 += wB0 + wB1;
        a1[0] += b2f_lo(vB0.x) * wB0 + b2f_lo(vB1.x) * wB1;
        a1[1] += b2f_hi(vB0.x) * wB0 + b2f_hi(vB1.x) * wB1;
        a1[2] += b2f_lo(vB0.y) * wB0 + b2f_lo(vB1.y) * wB1;
        a1[3] += b2f_hi(vB0.y) * wB0 + b2f_hi(vB1.y) * wB1;
        a1[4] += b2f_lo(vB0.z) * wB0 + b2f_lo(vB1.z) * wB1;
        a1[5] += b2f_hi(vB0.z) * wB0 + b2f_hi(vB1.z) * wB1;
        a1[6] += b2f_lo(vB0.w) * wB0 + b2f_lo(vB1.w) * wB1;
        a1[7] += b2f_hi(vB0.w) * wB0 + b2f_hi(vB1.w) * wB1;
      }
    }
  } else {
    if (ca > 0) {
      int2 r0 = recs[j0a];
      int2 r1 = recs[j0a + ((1 < ca) ? 1 : 0)];
      int2 r2 = recs[j0a + ((2 < ca) ? 2 : 0)];
      int2 r3 = recs[j0a + ((3 < ca) ? 3 : 0)];
      const int nit = (ca + 3) >> 2;
      for (int it = 0; it < nit; ++it) {
        const int b = it * 4;
        const float w0 = (b < ca)     ? __int_as_float(r0.y) : 0.f;
        const float w1 = (b + 1 < ca) ? __int_as_float(r1.y) : 0.f;
        const float w2 = (b + 2 < ca) ? __int_as_float(r2.y) : 0.f;
        const float w3 = (b + 3 < ca) ? __int_as_float(r3.y) : 0.f;
        const uint4 v0 = *(const uint4*)((const char*)rtA + (((unsigned)r0.x & OMASK) + coloff));
        const uint4 v1 = *(const uint4*)((const char*)rtA + (((unsigned)r1.x & OMASK) + coloff));
        const uint4 v2 = *(const uint4*)((const char*)rtA + (((unsigned)r2.x & OMASK) + coloff));
        const uint4 v3 = *(const uint4*)((const char*)rtA + (((unsigned)r3.x & OMASK) + coloff));
        const int nb = b + 4;
        r0 = recs[j0a + ((nb < ca) ? nb : 0)];
        r1 = recs[j0a + ((nb + 1 < ca) ? nb + 1 : 0)];
        r2 = recs[j0a + ((nb + 2 < ca) ? nb + 2 : 0)];
        r3 = recs[j0a + ((nb + 3 < ca) ? nb + 3 : 0)];
        ds0 += (w0 + w1) + (w2 + w3);
        a0[0] += b2f_lo(v0.x) * w0 + b2f_lo(v1.x) * w1 + b2f_lo(v2.x) * w2 + b2f_lo(v3.x) * w3;
        a0[1] += b2f_hi(v0.x) * w0 + b2f_hi(v1.x) * w1 + b2f_hi(v2.x) * w2 + b2f_hi(v3.x) * w3;
        a0[2] += b2f_lo(v0.y) * w0 + b2f_lo(v1.y) * w1 + b2f_lo(v2.y) * w2 + b2f_lo(v3.y) * w3;
        a0[3] += b2f_hi(v0.y) * w0 + b2f_hi(v1.y) * w1 + b2f_hi(v2.y) * w2 + b2f_hi(v3.y) * w3;
        a0[4] += b2f_lo(v0.z) * w0 + b2f_lo(v1.z) * w1 + b2f_lo(v2.z) * w2 + b2f_lo(v3.z) * w3;
        a0[5] += b2f_hi(v0.z) * w0 + b2f_hi(v1.z) * w1 + b2f_hi(v2.z) * w2 + b2f_hi(v3.z) * w3;
        a0[6] += b2f_lo(v0.w) * w0 + b2f_lo(v1.w) * w1 + b2f_lo(v2.w) * w2 + b2f_lo(v3.w) * w3;
        a0[7] += b2f_hi(v0.w) * w0 + b2f_hi(v1.w) * w1 + b2f_hi(v2.w) * w2 + b2f_hi(v3.w) * w3;
      }
    }
  }

  // ---- epilogue (per quarter; ds is lane-uniform within the quarter) ----
  const float inv0 = 1.f / (ds0 + 1e-16f);
  const float inv1 = 1.f / (ds1 + 1e-16f);
  float g0[8], g1[8], self[8];
#pragma unroll
  for (int c = 0; c < 8; ++c) { g0[c] = a0[c] * inv0; g1[c] = a1[c] * inv1; }
  {
    const ushort* lbp = isGene ? lb_gene + (size_t)node * 128
                               : lb_prot + (size_t)(node - NG) * 128;
    uint4 sv = *(const uint4*)(lbp + l16 * 8);
    self[0] = b2f_lo(sv.x); self[1] = b2f_hi(sv.x);
    self[2] = b2f_lo(sv.y); self[3] = b2f_hi(sv.y);
    self[4] = b2f_lo(sv.z); self[5] = b2f_hi(sv.z);
    self[6] = b2f_lo(sv.w); self[7] = b2f_hi(sv.w);
  }

  const float* cW = isGene ? cgW : cpW;
  const float cb = isGene ? cgb[0] : cpb[0];
  const float4 wlo = *(const float4*)(cW + l16 * 8);
  const float4 whi = *(const float4*)(cW + l16 * 8 + 4);
  float p0 = g0[0] * wlo.x + g0[1] * wlo.y + g0[2] * wlo.z + g0[3] * wlo.w +
             g0[4] * whi.x + g0[5] * whi.y + g0[6] * whi.z + g0[7] * whi.w;
  float p1 = g1[0] * wlo.x + g1[1] * wlo.y + g1[2] * wlo.z + g1[3] * wlo.w +
             g1[4] * whi.x + g1[5] * whi.y + g1[6] * whi.z + g1[7] * whi.w;
  float ps = self[0] * wlo.x + self[1] * wlo.y + self[2] * wlo.z + self[3] * wlo.w +
             self[4] * whi.x + self[5] * whi.y + self[6] * whi.z + self[7] * whi.w;
#pragma unroll
  for (int m = 8; m >= 1; m >>= 1) {  // reduce the quarter's 16 col-lanes
    p0 += __shfl_xor(p0, m, 64);
    p1 += __shfl_xor(p1, m, 64);
    ps += __shfl_xor(ps, m, 64);
  }
  const float s0 = p0 + cb, s1 = p1 + cb, ss = ps + cb;
  const float mx = isGene ? fmaxf(fmaxf(s0, s1), ss) : fmaxf(s0, ss);
  const float e0 = expf(s0 - mx);
  const float e1 = isGene ? expf(s1 - mx) : 0.f;
  const float es = expf(ss - mx);
  const float sum = e0 + e1 + es;
  const float b0 = e0 / sum, b1 = e1 / sum, bs = es / sum;

  float4 o0, o1;
  o0.x = fmaxf(g0[0] * b0 + g1[0] * b1 + self[0] * bs, 0.f);
  o0.y = fmaxf(g0[1] * b0 + g1[1] * b1 + self[1] * bs, 0.f);
  o0.z = fmaxf(g0[2] * b0 + g1[2] * b1 + self[2] * bs, 0.f);
  o0.w = fmaxf(g0[3] * b0 + g1[3] * b1 + self[3] * bs, 0.f);
  o1.x = fmaxf(g0[4] * b0 + g1[4] * b1 + self[4] * bs, 0.f);
  o1.y = fmaxf(g0[5] * b0 + g1[5] * b1 + self[5] * bs, 0.f);
  o1.z = fmaxf(g0[6] * b0 + g1[6] * b1 + self[6] * bs, 0.f);
  o1.w = fmaxf(g0[7] * b0 + g1[7] * b1 + self[7] * bs, 0.f);
  float* op = isGene ? out_gene + (size_t)node * 128
                     : out_prot + (size_t)(node - NG) * 128;
  *(float4*)(op + l16 * 8) = o0;
  *(float4*)(op + l16 * 8 + 4) = o1;
}

// ---------------------------------------------------------------------------
extern "C" void kernel_launch(void* const* d_in, const int* in_sizes, int n_in,
                              void* d_out, int out_size, void* d_ws,
                              size_t ws_size, hipStream_t stream) {
  const float* x_gene  = (const float*)d_in[0];
  const float* x_prot  = (const float*)d_in[1];
  const float* Wl_gene = (const float*)d_in[2];
  const float* bl_gene = (const float*)d_in[3];
  const float* Wr_gene = (const float*)d_in[4];
  const float* br_gene = (const float*)d_in[5];
  const float* Wl_prot = (const float*)d_in[6];
  const float* bl_prot = (const float*)d_in[7];
  const float* Wr_prot = (const float*)d_in[8];
  const float* br_prot = (const float*)d_in[9];
  const float* alW     = (const float*)d_in[10];  // [3,32,128] contiguous
  const float* alb     = (const float*)d_in[11];  // [3,32] contiguous
  const float* arW     = (const float*)d_in[12];
  const float* arb     = (const float*)d_in[13];
  const float* qw      = (const float*)d_in[14];  // [3,64,1]
  const float* sharp   = (const float*)d_in[15];
  const float* cgW     = (const float*)d_in[16];
  const float* cgb     = (const float*)d_in[17];
  const float* cpW     = (const float*)d_in[18];
  const float* cpb     = (const float*)d_in[19];
  const int* e_gg      = (const int*)d_in[20];
  const int* e_gp      = (const int*)d_in[21];
  const int* e_pp      = (const int*)d_in[22];

  const int NG = in_sizes[0] / 256;
  const int NP = in_sizes[1] / 256;
  const int E  = in_sizes[20] / 2;
  const int NPG = (NG + 127) & ~127;
  const int NPP = (NP + 127) & ~127;
  const int NT = 2 * NG + NP;          // concatenated head-node space
  const int NR = NG + 2 * NP;          // concatenated tail-node space (tr)

  char* base = (char*)d_ws;
  size_t off = 0;
  auto alloc = [&](size_t bytes) {
    void* p = base + off;
    off = (off + bytes + 255) & ~(size_t)255;
    return p;
  };
  ushort* xb_gene = (ushort*)alloc((size_t)NPG * 256 * 2);
  ushort* xb_prot = (ushort*)alloc((size_t)NPP * 256 * 2);

  ushort* Wlr_gene = (ushort*)alloc(256 * 256 * 2);
  ushort* Wlr_prot = (ushort*)alloc(256 * 256 * 2);
  ushort* alWb     = (ushort*)alloc(96 * 128 * 2);
  ushort* arWb     = (ushort*)alloc(96 * 128 * 2);
  ushort* lb_gene  = (ushort*)alloc((size_t)NPG * 128 * 2);
  ushort* rb_gene  = (ushort*)alloc((size_t)NPG * 128 * 2);
  ushort* lb_prot  = (ushort*)alloc((size_t)NPP * 128 * 2);
  ushort* rb_prot  = (ushort*)alloc((size_t)NPP * 128 * 2);
  int*    deg      = (int*)alloc((size_t)NT * 4);
  int*    offsets  = (int*)alloc((size_t)(NT + 1) * 4);
  const int TILES  = (NT + 2047) / 2048;
  int*    tile_tot = (int*)alloc((size_t)TILES * 4);
  int*    tile_pre = (int*)alloc((size_t)TILES * 4);
  int*    rank     = (int*)alloc((size_t)(3 * E) * 4);
  int2*   recs     = (int2*)alloc((size_t)(3 * E) * sizeof(int2));
  float*  tl3      = (float*)alloc((size_t)NT * 4);
  float*  tr3      = (float*)alloc((size_t)NR * 4);

  float* out_gene = (float*)d_out;
  float* out_prot = out_gene + (size_t)NG * 128;

  dim3 blk(256);

  // ---- 0) batched bf16 conversions (1 dispatch) ----
  {
    CvtArgs a;
    const float* srcs[8] = {x_gene, x_prot, Wl_gene, Wr_gene, Wl_prot, Wr_prot, alW, arW};
    ushort* dsts[8] = {xb_gene, xb_prot, Wlr_gene, Wlr_gene + 128 * 256,
                       Wlr_prot, Wlr_prot + 128 * 256, alWb, arWb};
    int valids[8] = {NG * 256, NP * 256, 128 * 256, 128 * 256, 128 * 256, 128 * 256, 96 * 128, 96 * 128};
    int totals[8] = {NPG * 256, NPP * 256, 128 * 256, 128 * 256, 128 * 256, 128 * 256, 96 * 128, 96 * 128};
    int b = 0;
    for (int j = 0; j < 8; ++j) {
      a.src[j] = srcs[j]; a.dst[j] = dsts[j];
      a.valid[j] = valids[j]; a.total[j] = totals[j];
      a.bstart[j] = b;
      b += (totals[j] / 4 + 255) / 256;
    }
    a.bstart[8] = b;
    cvt_multi<<<b, blk, 0, stream>>>(a);
  }

  // ---- 1) fused l/r projections, both node types (1 dispatch) ----
  {
    ProjArgs p;
    p.xb[0] = xb_gene; p.xb[1] = xb_prot;
    p.Wb[0] = Wlr_gene; p.Wb[1] = Wlr_prot;
    p.bl[0] = bl_gene; p.bl[1] = bl_prot;
    p.br[0] = br_gene; p.br[1] = br_prot;
    p.lb[0] = lb_gene; p.lb[1] = lb_prot;
    p.rb[0] = rb_gene; p.rb[1] = rb_prot;
    p.N[0] = NG; p.N[1] = NP;
    proj_lr_mfma<<<dim3(NPG / 128, 2, 2), blk, 0, stream>>>(p);
  }

  // ---- 2) attention projections + fused tanh-dot -> tl3/tr3 (1 dispatch) --
  {
    AttnArgs a;
    a.Ab[0] = lb_gene; a.Wb[0] = alWb;            a.bias[0] = alb;      a.N[0] = NG; a.BN[0] = 64;
    a.q0[0] = qw + 0;  a.q1[0] = qw + 64;  a.o0[0] = tl3;          a.o1[0] = tl3 + NG;
    a.Ab[1] = rb_gene; a.Wb[1] = arWb;            a.bias[1] = arb;      a.N[1] = NG; a.BN[1] = 32;
    a.q0[1] = qw + 32; a.q1[1] = qw + 32;  a.o0[1] = tr3;          a.o1[1] = tr3;
    a.Ab[2] = lb_prot; a.Wb[2] = alWb + 64 * 128; a.bias[2] = alb + 64; a.N[2] = NP; a.BN[2] = 32;
    a.q0[2] = qw + 128; a.q1[2] = qw + 128; a.o0[2] = tl3 + 2 * NG; a.o1[2] = tl3 + 2 * NG;
    a.Ab[3] = rb_prot; a.Wb[3] = arWb + 32 * 128; a.bias[3] = arb + 32; a.N[3] = NP; a.BN[3] = 64;
    a.q0[3] = qw + 96; a.q1[3] = qw + 160; a.o0[3] = tr3 + NG;     a.o1[3] = tr3 + NG + NP;
    attn_proj_multi<<<dim3(NPG / 128, 4), blk, 0, stream>>>(a);
  }

  // ---- 3) CSR build (hist+rank -> scan -> scatter{d*256,w}) ----
  const int gridE3 = (3 * E + 255) / 256;
  hipMemsetAsync(deg, 0, (size_t)NT * sizeof(int), stream);
  hist3_kernel<<<gridE3, blk, 0, stream>>>(e_gg, e_gp, e_pp, deg, rank, E, NG);
  scanA_kernel<<<TILES, blk, 0, stream>>>(deg, offsets, tile_tot, NT);
  scanB_kernel<<<1, blk, 0, stream>>>(tile_tot, tile_pre, offsets, TILES, NT);
  scanC_kernel<<<TILES, blk, 0, stream>>>(offsets, tile_pre, NT);
  scatter3_kernel<<<gridE3, blk, 0, stream>>>(e_gg, e_gp, e_pp, rank, offsets,
                                              tl3, tr3, sharp, recs, E, NG, NP);

  // ---- 4) fused gather + relation combine (1 dispatch) ----
  gather_combine<<<(NG + NP + 15) / 16, blk, 0, stream>>>(
      rb_gene, rb_prot, lb_gene, lb_prot, offsets, recs,
      cgW, cgb, cpW, cpb, out_gene, out_prot, NG, NP);
}

// Round 5
// 407.883 us; speedup vs baseline: 1.1433x; 1.0536x over previous
//
#include <hip/hip_runtime.h>
#include <hip/hip_bf16.h>

// ---------------------------------------------------------------------------
// LATTE heterogeneous GNN layer (gene/protein).
// R13: (a) proj_lr consumes x fp32 DIRECTLY (reg-staged f2b convert, same
//      rounding as cvt -> bit-identical) and computes BOTH col-halves per
//      512-thread block: x read once, xb buffer + the x-part of cvt_multi
//      (153 MB round-trip) are gone. cvt is weights-only (~310 KB).
//      (b) gather gene path deepened to 4 edges/relation/iter (8 rows +
//      8 recs in flight per quarter) -> 2x MLP, half the latency epochs.
// ---------------------------------------------------------------------------

typedef __attribute__((ext_vector_type(8))) short short8;   // 8 bf16
typedef __attribute__((ext_vector_type(4))) float floatx4;  // 4 f32 acc

__device__ __forceinline__ void gload16(const void* g, void* l) {
  __builtin_amdgcn_global_load_lds(
      (const __attribute__((address_space(1))) void*)g,
      (__attribute__((address_space(3))) void*)l, 16, 0, 0);
}

__device__ __forceinline__ ushort f2b(float x) {
  __hip_bfloat16 h = __float2bfloat16(x);
  return *reinterpret_cast<ushort*>(&h);
}
__device__ __forceinline__ float b2f_lo(unsigned v) { return __uint_as_float(v << 16); }
__device__ __forceinline__ float b2f_hi(unsigned v) { return __uint_as_float(v & 0xffff0000u); }

// ---------------- batched fp32 -> bf16 convert (weights only) --------------
struct CvtArgs {
  const float* src[8];
  ushort* dst[8];
  int valid[8];
  int total[8];
  int bstart[9];
};
__global__ __launch_bounds__(256) void cvt_multi(CvtArgs a) {
  int b = blockIdx.x;
  int e = 0;
#pragma unroll
  for (int j = 1; j < 8; ++j)
    if (b >= a.bstart[j]) e = j;
  int i = ((b - a.bstart[e]) * 256 + threadIdx.x) * 4;
  if (i >= a.total[e]) return;
  float4 v = make_float4(0.f, 0.f, 0.f, 0.f);
  if (i < a.valid[e]) v = *(const float4*)(a.src[e] + i);
  ushort4 o;
  o.x = f2b(v.x); o.y = f2b(v.y); o.z = f2b(v.z); o.w = f2b(v.w);
  *(ushort4*)(a.dst[e] + i) = o;
}

// ------------- fused l/r projection: [NPAD,256]f32 @ [256,256]^T -----------
// 512 threads, 8 waves (2 row-halves x 4 col-strips of 64). A tile is
// reg-staged from fp32 x with f2b (identical rounding to the old cvt path);
// B (bf16 Wlr, both halves) via global_load_lds. x is read exactly once.
struct ProjArgs {
  const float* x[2];
  const ushort* Wb[2];
  const float* bl[2];
  const float* br[2];
  ushort* lb[2];
  ushort* rb[2];
  int N[2];
};
__global__ __launch_bounds__(512) void proj_lr_mfma(ProjArgs g) {
  const int ty = blockIdx.y;
  const float* xp = g.x[ty];
  const int N = g.N[ty];
  __shared__ ushort As[128 * 32];
  __shared__ ushort Bs[256 * 32];
  const int tid = threadIdx.x;
  const int lane = tid & 63;
  const int wave = tid >> 6;               // 0..7
  const int wm = wave & 1, wn = wave >> 1; // wn 0..3 -> col strip of 64
  const int rowBase = blockIdx.x * 128;
  const ushort* Wb = g.Wb[ty];

  floatx4 acc[4][4] = {};

  const int arow = tid >> 2, achk = tid & 3;       // A: 128 rows x 4 chunks
  const int xrow = min(rowBase + arow, N - 1);     // clamp: pad rows dup last
  const float* xrp = xp + (size_t)xrow * 256;

  for (int k0 = 0; k0 < 256; k0 += 32) {
    // B: 256 rows x 32 k (bf16) = 1024 x 16B chunks / 512 threads = 2 each
#pragma unroll
    for (int i = 0; i < 2; ++i) {
      int t = tid + i * 512;
      gload16(Wb + (size_t)(t >> 2) * 256 + k0 + (t & 3) * 8, &Bs[t * 8]);
    }
    // A: 8 fp32 -> 8 bf16 -> one 16B ds_write
    float4 lo = *(const float4*)(xrp + k0 + achk * 8);
    float4 hi = *(const float4*)(xrp + k0 + achk * 8 + 4);
    ushort4 c0, c1;
    c0.x = f2b(lo.x); c0.y = f2b(lo.y); c0.z = f2b(lo.z); c0.w = f2b(lo.w);
    c1.x = f2b(hi.x); c1.y = f2b(hi.y); c1.z = f2b(hi.z); c1.w = f2b(hi.w);
    *(ushort4*)&As[arow * 32 + achk * 8] = c0;
    *(ushort4*)&As[arow * 32 + achk * 8 + 4] = c1;
    __syncthreads();
    short8 bf[4];
#pragma unroll
    for (int nt = 0; nt < 4; ++nt)
      bf[nt] = *(const short8*)&Bs[(wn * 64 + nt * 16 + (lane & 15)) * 32 + (lane >> 4) * 8];
#pragma unroll
    for (int mt = 0; mt < 4; ++mt) {
      short8 a = *(const short8*)&As[(wm * 64 + mt * 16 + (lane & 15)) * 32 + (lane >> 4) * 8];
#pragma unroll
      for (int nt = 0; nt < 4; ++nt)
        acc[mt][nt] = __builtin_amdgcn_mfma_f32_16x16x32_bf16(a, bf[nt], acc[mt][nt], 0, 0, 0);
    }
    __syncthreads();
  }

#pragma unroll
  for (int mt = 0; mt < 4; ++mt)
#pragma unroll
    for (int nt = 0; nt < 4; ++nt) {
      const int col = wn * 64 + nt * 16 + (lane & 15);   // 0..255
      const int half = col >> 7, c = col & 127;          // wave-uniform half
      const float bv = (half ? g.br[ty] : g.bl[ty])[c];
      ushort* outp = half ? g.rb[ty] : g.lb[ty];
#pragma unroll
      for (int vi = 0; vi < 4; ++vi) {
        int row = rowBase + wm * 64 + mt * 16 + (lane >> 4) * 4 + vi;
        if (row < N) outp[(size_t)row * 128 + c] = f2b(acc[mt][nt][vi] + bv);
      }
    }
}

// ------------- batched attention projection + FUSED tanh-dot ---------------
struct AttnArgs {
  const ushort* Ab[4];
  const ushort* Wb[4];
  const float* bias[4];
  const float* q0[4];   // cols 0..31
  const float* q1[4];   // cols 32..63 (entries with BN=64)
  float* o0[4];
  float* o1[4];
  int N[4];
  int BN[4];
};
__global__ __launch_bounds__(256) void attn_proj_multi(AttnArgs g) {
  const int ei = blockIdx.y;
  const ushort* Ab = g.Ab[ei];
  const ushort* Wb = g.Wb[ei];
  const int N = g.N[ei], BN = g.BN[ei];
  const int NB = BN >> 4;
  __shared__ ushort As[128 * 32];
  __shared__ ushort Ws[64 * 128];
  const int tid = threadIdx.x;
  const int lane = tid & 63;
  const int wave = tid >> 6;
  const int rowBase = blockIdx.x * 128;

  for (int i = 0; i < NB; ++i) {
    int idx = tid + i * 256;
    gload16(Wb + (size_t)idx * 8, &Ws[idx * 8]);
  }

  floatx4 acc[2][4] = {};
  for (int k0 = 0; k0 < 128; k0 += 32) {
#pragma unroll
    for (int i = 0; i < 2; ++i) {
      int t = tid + i * 256;
      gload16(Ab + (size_t)(rowBase + (t >> 2)) * 128 + k0 + (t & 3) * 8, &As[t * 8]);
    }
    __syncthreads();
    short8 bf[4];
#pragma unroll
    for (int nt = 0; nt < 4; ++nt)
      if (nt < NB)
        bf[nt] = *(const short8*)&Ws[(nt * 16 + (lane & 15)) * 128 + k0 + (lane >> 4) * 8];
#pragma unroll
    for (int mt = 0; mt < 2; ++mt) {
      short8 a = *(const short8*)&As[(wave * 32 + mt * 16 + (lane & 15)) * 32 + (lane >> 4) * 8];
#pragma unroll
      for (int nt = 0; nt < 4; ++nt)
        if (nt < NB)
          acc[mt][nt] = __builtin_amdgcn_mfma_f32_16x16x32_bf16(a, bf[nt], acc[mt][nt], 0, 0, 0);
    }
    __syncthreads();
  }

  // ---- fused epilogue: tanh-dot reduce into per-row scalars ----
  const float* bias = g.bias[ei];
  const int l15 = lane & 15;
  const bool two = (NB == 4);
  float bv[4];
#pragma unroll
  for (int nt = 0; nt < 4; ++nt) bv[nt] = (nt < NB) ? bias[nt * 16 + l15] : 0.f;
  float q0v0 = g.q0[ei][l15], q0v1 = g.q0[ei][16 + l15];
  float q1v0 = 0.f, q1v1 = 0.f;
  if (two) { q1v0 = g.q1[ei][l15]; q1v1 = g.q1[ei][16 + l15]; }
  float* o0 = g.o0[ei];
  float* o1 = g.o1[ei];
#pragma unroll
  for (int mt = 0; mt < 2; ++mt)
#pragma unroll
    for (int vi = 0; vi < 4; ++vi) {
      float slo = tanhf(acc[mt][0][vi] + bv[0]) * q0v0
                + tanhf(acc[mt][1][vi] + bv[1]) * q0v1;
      float shi = 0.f;
      if (two)
        shi = tanhf(acc[mt][2][vi] + bv[2]) * q1v0
            + tanhf(acc[mt][3][vi] + bv[3]) * q1v1;
#pragma unroll
      for (int m = 8; m >= 1; m >>= 1) {
        slo += __shfl_xor(slo, m, 64);   // xor<16 stays in the 16-lane group
        shi += __shfl_xor(shi, m, 64);
      }
      const int row = rowBase + wave * 32 + mt * 16 + (lane >> 4) * 4 + vi;
      if (l15 == 0 && row < N) {
        o0[row] = slo;
        if (two) o1[row] = shi;
      }
    }
}

// ------- hist + rank: deg count and per-edge rank (coalesced) -------------
__global__ __launch_bounds__(256) void hist3_kernel(
    const int* __restrict__ e0, const int* __restrict__ e1,
    const int* __restrict__ e2, int* __restrict__ deg,
    int* __restrict__ rank, int E, int NG) {
  int e = blockIdx.x * 256 + threadIdx.x;
  if (e >= 3 * E) return;
  int mp = (e >= 2 * E) ? 2 : ((e >= E) ? 1 : 0);
  int el = e - mp * E;
  const int* ep = (mp == 0) ? e0 : (mp == 1) ? e1 : e2;
  int segb = (mp == 2) ? 2 * NG : mp * NG;
  rank[e] = atomicAdd(&deg[segb + ep[el]], 1);
}

// ------- hierarchical scan: A) tile scan, B) partials, C) add prefix ------
__global__ __launch_bounds__(256) void scanA_kernel(
    const int* __restrict__ deg, int* __restrict__ offsets,
    int* __restrict__ tile_tot, int n) {
  __shared__ int wtot[4];
  const int t = threadIdx.x;
  const int base = blockIdx.x * 2048 + t * 8;
  int v[8], pre[8], s = 0;
#pragma unroll
  for (int j = 0; j < 8; ++j) {
    v[j] = (base + j < n) ? deg[base + j] : 0;
    pre[j] = s;
    s += v[j];
  }
  const int lane = t & 63, wv = t >> 6;
  int x = s;
#pragma unroll
  for (int o = 1; o < 64; o <<= 1) {
    int u = __shfl_up(x, o, 64);
    if (lane >= o) x += u;
  }
  if (lane == 63) wtot[wv] = x;
  __syncthreads();
  int wpre = 0;
#pragma unroll
  for (int j = 0; j < 4; ++j) wpre += (j < wv) ? wtot[j] : 0;
  int excl = wpre + x - s;
#pragma unroll
  for (int j = 0; j < 8; ++j)
    if (base + j < n) offsets[base + j] = excl + pre[j];
  if (t == 255) tile_tot[blockIdx.x] = wpre + x;
}

__global__ __launch_bounds__(256) void scanB_kernel(
    const int* __restrict__ tile_tot, int* __restrict__ tile_pre,
    int* __restrict__ offsets, int T, int n) {
  __shared__ int wtot[4];
  const int t = threadIdx.x;
  int v = (t < T) ? tile_tot[t] : 0;
  const int lane = t & 63, wv = t >> 6;
  int x = v;
#pragma unroll
  for (int o = 1; o < 64; o <<= 1) {
    int u = __shfl_up(x, o, 64);
    if (lane >= o) x += u;
  }
  if (lane == 63) wtot[wv] = x;
  __syncthreads();
  int wpre = 0;
#pragma unroll
  for (int j = 0; j < 4; ++j) wpre += (j < wv) ? wtot[j] : 0;
  if (t < T) tile_pre[t] = wpre + x - v;
  if (t == 255) offsets[n] = wpre + x;  // grand total
}

__global__ __launch_bounds__(256) void scanC_kernel(
    int* __restrict__ offsets, const int* __restrict__ tile_pre, int n) {
  const int add = tile_pre[blockIdx.x];
  const int base = blockIdx.x * 2048 + threadIdx.x * 8;
#pragma unroll
  for (int j = 0; j < 8; ++j)
    if (base + j < n) offsets[base + j] += add;
}

// ------- scatter3: pos = offsets[node] + rank[e]; writes {d*256, w} -------
__global__ __launch_bounds__(256) void scatter3_kernel(
    const int* __restrict__ e0, const int* __restrict__ e1,
    const int* __restrict__ e2, const int* __restrict__ rank,
    const int* __restrict__ offsets,
    const float* __restrict__ tl3, const float* __restrict__ tr3,
    const float* __restrict__ sharp, int2* __restrict__ recs,
    int E, int NG, int NP) {
  int e = blockIdx.x * 256 + threadIdx.x;
  if (e >= 3 * E) return;
  int mp = (e >= 2 * E) ? 2 : ((e >= E) ? 1 : 0);
  int el = e - mp * E;
  const int* ep = (mp == 0) ? e0 : (mp == 1) ? e1 : e2;
  int s = ep[el], d = ep[el + E];
  int hb = (mp == 2) ? 2 * NG : mp * NG;                 // head/offsets base
  int tb = (mp == 0) ? 0 : (mp == 1) ? NG : NG + NP;     // tr3 segment base
  // |tl+tr| <= sum|qw| ~ 10 -> exp safe in fp32 without max-shift.
  float w = expf((tl3[hb + s] + tr3[tb + d]) * sharp[mp]);
  recs[offsets[hb + s] + rank[e]] = make_int2(d << 8, __float_as_int(w));
}

// ------- fused gather + relation combine: QUARTER per OUTPUT node ---------
// Each 16-lane quarter owns one node (4 nodes/wave). Gene path: 4 edges per
// relation per iteration (8 rows + 8 recs in flight) with record prefetch.
// Clamped lanes re-read index j0 (weight forced 0); row offsets masked to
// stay in-workspace.
__global__ __launch_bounds__(256) void gather_combine(
    const ushort* __restrict__ rb_gene, const ushort* __restrict__ rb_prot,
    const ushort* __restrict__ lb_gene, const ushort* __restrict__ lb_prot,
    const int* __restrict__ offsets, const int2* __restrict__ recs,
    const float* __restrict__ cgW, const float* __restrict__ cgb,
    const float* __restrict__ cpW, const float* __restrict__ cpb,
    float* __restrict__ out_gene, float* __restrict__ out_prot,
    int NG, int NP) {
  const int lane = threadIdx.x & 63;
  const int l16 = lane & 15;
  const int node = blockIdx.x * 16 + (threadIdx.x >> 4);
  if (node >= NG + NP) return;
  const bool isGene = node < NG;
  const unsigned coloff = (unsigned)l16 << 4;   // 16 B per lane
  const unsigned OMASK = 0x00FFFF00u;           // bounds stray row offsets

  const int h0 = isGene ? node : NG + node;     // gg for genes / pp for prots
  const int j0a = offsets[h0];
  const int ca = offsets[h0 + 1] - j0a;
  int j0b = 0, cb2 = 0;
  if (isGene) {
    j0b = offsets[NG + node];
    cb2 = offsets[NG + node + 1] - j0b;
  }

  float a0[8] = {0.f, 0.f, 0.f, 0.f, 0.f, 0.f, 0.f, 0.f};
  float a1[8] = {0.f, 0.f, 0.f, 0.f, 0.f, 0.f, 0.f, 0.f};
  float ds0 = 0.f, ds1 = 0.f;
  const ushort* rtA = isGene ? rb_gene : rb_prot;

  if (isGene) {
    const int cmax = (ca > cb2) ? ca : cb2;
    if (cmax > 0) {
      int2 rA[4], rB[4];
#pragma unroll
      for (int p = 0; p < 4; ++p) {
        rA[p] = recs[j0a + ((p < ca) ? p : 0)];
        rB[p] = recs[j0b + ((p < cb2) ? p : 0)];
      }
      const int nit = (cmax + 3) >> 2;
      for (int it = 0; it < nit; ++it) {
        const int b = it * 4;
        float wA[4], wB[4];
        uint4 vA[4], vB[4];
#pragma unroll
        for (int p = 0; p < 4; ++p) {
          wA[p] = (b + p < ca)  ? __int_as_float(rA[p].y) : 0.f;
          wB[p] = (b + p < cb2) ? __int_as_float(rB[p].y) : 0.f;
          vA[p] = *(const uint4*)((const char*)rtA + (((unsigned)rA[p].x & OMASK) + coloff));
          vB[p] = *(const uint4*)((const char*)rb_prot + (((unsigned)rB[p].x & OMASK) + coloff));
        }
        const int nb = b + 4;
#pragma unroll
        for (int p = 0; p < 4; ++p) {
          rA[p] = recs[j0a + ((nb + p < ca) ? nb + p : 0)];
          rB[p] = recs[j0b + ((nb + p < cb2) ? nb + p : 0)];
        }
#pragma unroll
        for (int p = 0; p < 4; ++p) {
          ds0 += wA[p];
          a0[0] += b2f_lo(vA[p].x) * wA[p]; a0[1] += b2f_hi(vA[p].x) * wA[p];
          a0[2] += b2f_lo(vA[p].y) * wA[p]; a0[3] += b2f_hi(vA[p].y) * wA[p];
          a0[4] += b2f_lo(vA[p].z) * wA[p]; a0[5] += b2f_hi(vA[p].z) * wA[p];
          a0[6] += b2f_lo(vA[p].w) * wA[p]; a0[7] += b2f_hi(vA[p].w) * wA[p];
          ds1 += wB[p];
          a1[0] += b2f_lo(vB[p].x) * wB[p]; a1[1] += b2f_hi(vB[p].x) * wB[p];
          a1[2] += b2f_lo(vB[p].y) * wB[p]; a1[3] += b2f_hi(vB[p].y) * wB[p];
          a1[4] += b2f_lo(vB[p].z) * wB[p]; a1[5] += b2f_hi(vB[p].z) * wB[p];
          a1[6] += b2f_lo(vB[p].w) * wB[p]; a1[7] += b2f_hi(vB[p].w) * wB[p];
        }
      }
    }
  } else {
    if (ca > 0) {
      int2 r0 = recs[j0a];
      int2 r1 = recs[j0a + ((1 < ca) ? 1 : 0)];
      int2 r2 = recs[j0a + ((2 < ca) ? 2 : 0)];
      int2 r3 = recs[j0a + ((3 < ca) ? 3 : 0)];
      const int nit = (ca + 3) >> 2;
      for (int it = 0; it < nit; ++it) {
        const int b = it * 4;
        const float w0 = (b < ca)     ? __int_as_float(r0.y) : 0.f;
        const float w1 = (b + 1 < ca) ? __int_as_float(r1.y) : 0.f;
        const float w2 = (b + 2 < ca) ? __int_as_float(r2.y) : 0.f;
        const float w3 = (b + 3 < ca) ? __int_as_float(r3.y) : 0.f;
        const uint4 v0 = *(const uint4*)((const char*)rtA + (((unsigned)r0.x & OMASK) + coloff));
        const uint4 v1 = *(const uint4*)((const char*)rtA + (((unsigned)r1.x & OMASK) + coloff));
        const uint4 v2 = *(const uint4*)((const char*)rtA + (((unsigned)r2.x & OMASK) + coloff));
        const uint4 v3 = *(const uint4*)((const char*)rtA + (((unsigned)r3.x & OMASK) + coloff));
        const int nb = b + 4;
        r0 = recs[j0a + ((nb < ca) ? nb : 0)];
        r1 = recs[j0a + ((nb + 1 < ca) ? nb + 1 : 0)];
        r2 = recs[j0a + ((nb + 2 < ca) ? nb + 2 : 0)];
        r3 = recs[j0a + ((nb + 3 < ca) ? nb + 3 : 0)];
        ds0 += (w0 + w1) + (w2 + w3);
        a0[0] += b2f_lo(v0.x) * w0 + b2f_lo(v1.x) * w1 + b2f_lo(v2.x) * w2 + b2f_lo(v3.x) * w3;
        a0[1] += b2f_hi(v0.x) * w0 + b2f_hi(v1.x) * w1 + b2f_hi(v2.x) * w2 + b2f_hi(v3.x) * w3;
        a0[2] += b2f_lo(v0.y) * w0 + b2f_lo(v1.y) * w1 + b2f_lo(v2.y) * w2 + b2f_lo(v3.y) * w3;
        a0[3] += b2f_hi(v0.y) * w0 + b2f_hi(v1.y) * w1 + b2f_hi(v2.y) * w2 + b2f_hi(v3.y) * w3;
        a0[4] += b2f_lo(v0.z) * w0 + b2f_lo(v1.z) * w1 + b2f_lo(v2.z) * w2 + b2f_lo(v3.z) * w3;
        a0[5] += b2f_hi(v0.z) * w0 + b2f_hi(v1.z) * w1 + b2f_hi(v2.z) * w2 + b2f_hi(v3.z) * w3;
        a0[6] += b2f_lo(v0.w) * w0 + b2f_lo(v1.w) * w1 + b2f_lo(v2.w) * w2 + b2f_lo(v3.w) * w3;
        a0[7] += b2f_hi(v0.w) * w0 + b2f_hi(v1.w) * w1 + b2f_hi(v2.w) * w2 + b2f_hi(v3.w) * w3;
      }
    }
  }

  // ---- epilogue (per quarter; ds is lane-uniform within the quarter) ----
  const float inv0 = 1.f / (ds0 + 1e-16f);
  const float inv1 = 1.f / (ds1 + 1e-16f);
  float g0[8], g1[8], self[8];
#pragma unroll
  for (int c = 0; c < 8; ++c) { g0[c] = a0[c] * inv0; g1[c] = a1[c] * inv1; }
  {
    const ushort* lbp = isGene ? lb_gene + (size_t)node * 128
                               : lb_prot + (size_t)(node - NG) * 128;
    uint4 sv = *(const uint4*)(lbp + l16 * 8);
    self[0] = b2f_lo(sv.x); self[1] = b2f_hi(sv.x);
    self[2] = b2f_lo(sv.y); self[3] = b2f_hi(sv.y);
    self[4] = b2f_lo(sv.z); self[5] = b2f_hi(sv.z);
    self[6] = b2f_lo(sv.w); self[7] = b2f_hi(sv.w);
  }

  const float* cW = isGene ? cgW : cpW;
  const float cb = isGene ? cgb[0] : cpb[0];
  const float4 wlo = *(const float4*)(cW + l16 * 8);
  const float4 whi = *(const float4*)(cW + l16 * 8 + 4);
  float p0 = g0[0] * wlo.x + g0[1] * wlo.y + g0[2] * wlo.z + g0[3] * wlo.w +
             g0[4] * whi.x + g0[5] * whi.y + g0[6] * whi.z + g0[7] * whi.w;
  float p1 = g1[0] * wlo.x + g1[1] * wlo.y + g1[2] * wlo.z + g1[3] * wlo.w +
             g1[4] * whi.x + g1[5] * whi.y + g1[6] * whi.z + g1[7] * whi.w;
  float ps = self[0] * wlo.x + self[1] * wlo.y + self[2] * wlo.z + self[3] * wlo.w +
             self[4] * whi.x + self[5] * whi.y + self[6] * whi.z + self[7] * whi.w;
#pragma unroll
  for (int m = 8; m >= 1; m >>= 1) {  // reduce the quarter's 16 col-lanes
    p0 += __shfl_xor(p0, m, 64);
    p1 += __shfl_xor(p1, m, 64);
    ps += __shfl_xor(ps, m, 64);
  }
  const float s0 = p0 + cb, s1 = p1 + cb, ss = ps + cb;
  const float mx = isGene ? fmaxf(fmaxf(s0, s1), ss) : fmaxf(s0, ss);
  const float e0 = expf(s0 - mx);
  const float e1 = isGene ? expf(s1 - mx) : 0.f;
  const float es = expf(ss - mx);
  const float sum = e0 + e1 + es;
  const float b0 = e0 / sum, b1 = e1 / sum, bs = es / sum;

  float4 o0, o1;
  o0.x = fmaxf(g0[0] * b0 + g1[0] * b1 + self[0] * bs, 0.f);
  o0.y = fmaxf(g0[1] * b0 + g1[1] * b1 + self[1] * bs, 0.f);
  o0.z = fmaxf(g0[2] * b0 + g1[2] * b1 + self[2] * bs, 0.f);
  o0.w = fmaxf(g0[3] * b0 + g1[3] * b1 + self[3] * bs, 0.f);
  o1.x = fmaxf(g0[4] * b0 + g1[4] * b1 + self[4] * bs, 0.f);
  o1.y = fmaxf(g0[5] * b0 + g1[5] * b1 + self[5] * bs, 0.f);
  o1.z = fmaxf(g0[6] * b0 + g1[6] * b1 + self[6] * bs, 0.f);
  o1.w = fmaxf(g0[7] * b0 + g1[7] * b1 + self[7] * bs, 0.f);
  float* op = isGene ? out_gene + (size_t)node * 128
                     : out_prot + (size_t)(node - NG) * 128;
  *(float4*)(op + l16 * 8) = o0;
  *(float4*)(op + l16 * 8 + 4) = o1;
}

// ---------------------------------------------------------------------------
extern "C" void kernel_launch(void* const* d_in, const int* in_sizes, int n_in,
                              void* d_out, int out_size, void* d_ws,
                              size_t ws_size, hipStream_t stream) {
  const float* x_gene  = (const float*)d_in[0];
  const float* x_prot  = (const float*)d_in[1];
  const float* Wl_gene = (const float*)d_in[2];
  const float* bl_gene = (const float*)d_in[3];
  const float* Wr_gene = (const float*)d_in[4];
  const float* br_gene = (const float*)d_in[5];
  const float* Wl_prot = (const float*)d_in[6];
  const float* bl_prot = (const float*)d_in[7];
  const float* Wr_prot = (const float*)d_in[8];
  const float* br_prot = (const float*)d_in[9];
  const float* alW     = (const float*)d_in[10];  // [3,32,128] contiguous
  const float* alb     = (const float*)d_in[11];  // [3,32] contiguous
  const float* arW     = (const float*)d_in[12];
  const float* arb     = (const float*)d_in[13];
  const float* qw      = (const float*)d_in[14];  // [3,64,1]
  const float* sharp   = (const float*)d_in[15];
  const float* cgW     = (const float*)d_in[16];
  const float* cgb     = (const float*)d_in[17];
  const float* cpW     = (const float*)d_in[18];
  const float* cpb     = (const float*)d_in[19];
  const int* e_gg      = (const int*)d_in[20];
  const int* e_gp      = (const int*)d_in[21];
  const int* e_pp      = (const int*)d_in[22];

  const int NG = in_sizes[0] / 256;
  const int NP = in_sizes[1] / 256;
  const int E  = in_sizes[20] / 2;
  const int NPG = (NG + 127) & ~127;
  const int NT = 2 * NG + NP;          // concatenated head-node space
  const int NR = NG + 2 * NP;          // concatenated tail-node space (tr)

  char* base = (char*)d_ws;
  size_t off = 0;
  auto alloc = [&](size_t bytes) {
    void* p = base + off;
    off = (off + bytes + 255) & ~(size_t)255;
    return p;
  };
  ushort* Wlr_gene = (ushort*)alloc(256 * 256 * 2);
  ushort* Wlr_prot = (ushort*)alloc(256 * 256 * 2);
  ushort* alWb     = (ushort*)alloc(96 * 128 * 2);
  ushort* arWb     = (ushort*)alloc(96 * 128 * 2);
  ushort* lb_gene  = (ushort*)alloc((size_t)NPG * 128 * 2);
  ushort* rb_gene  = (ushort*)alloc((size_t)NPG * 128 * 2);
  ushort* lb_prot  = (ushort*)alloc((size_t)NPG * 128 * 2);
  ushort* rb_prot  = (ushort*)alloc((size_t)NPG * 128 * 2);
  int*    deg      = (int*)alloc((size_t)NT * 4);
  int*    offsets  = (int*)alloc((size_t)(NT + 1) * 4);
  const int TILES  = (NT + 2047) / 2048;
  int*    tile_tot = (int*)alloc((size_t)TILES * 4);
  int*    tile_pre = (int*)alloc((size_t)TILES * 4);
  int*    rank     = (int*)alloc((size_t)(3 * E) * 4);
  int2*   recs     = (int2*)alloc((size_t)(3 * E) * sizeof(int2));
  float*  tl3      = (float*)alloc((size_t)NT * 4);
  float*  tr3      = (float*)alloc((size_t)NR * 4);

  float* out_gene = (float*)d_out;
  float* out_prot = out_gene + (size_t)NG * 128;

  dim3 blk(256);

  // ---- 0) bf16 conversions, weights only (1 tiny dispatch) ----
  {
    CvtArgs a;
    const float* srcs[8] = {Wl_gene, Wr_gene, Wl_prot, Wr_prot, alW, arW,
                            Wl_gene, Wl_gene};
    ushort* dsts[8] = {Wlr_gene, Wlr_gene + 128 * 256,
                       Wlr_prot, Wlr_prot + 128 * 256, alWb, arWb,
                       Wlr_gene, Wlr_gene};
    int sizes[8] = {128 * 256, 128 * 256, 128 * 256, 128 * 256,
                    96 * 128, 96 * 128, 0, 0};
    int b = 0;
    for (int j = 0; j < 8; ++j) {
      a.src[j] = srcs[j]; a.dst[j] = dsts[j];
      a.valid[j] = sizes[j]; a.total[j] = sizes[j];
      a.bstart[j] = b;
      b += (sizes[j] / 4 + 255) / 256;
    }
    a.bstart[8] = b;
    cvt_multi<<<b, blk, 0, stream>>>(a);
  }

  // ---- 1) fused l/r projections from fp32 x, both halves (1 dispatch) ----
  {
    ProjArgs p;
    p.x[0] = x_gene; p.x[1] = x_prot;
    p.Wb[0] = Wlr_gene; p.Wb[1] = Wlr_prot;
    p.bl[0] = bl_gene; p.bl[1] = bl_prot;
    p.br[0] = br_gene; p.br[1] = br_prot;
    p.lb[0] = lb_gene; p.lb[1] = lb_prot;
    p.rb[0] = rb_gene; p.rb[1] = rb_prot;
    p.N[0] = NG; p.N[1] = NP;
    proj_lr_mfma<<<dim3(NPG / 128, 2), dim3(512), 0, stream>>>(p);
  }

  // ---- 2) attention projections + fused tanh-dot -> tl3/tr3 (1 dispatch) --
  {
    AttnArgs a;
    a.Ab[0] = lb_gene; a.Wb[0] = alWb;            a.bias[0] = alb;      a.N[0] = NG; a.BN[0] = 64;
    a.q0[0] = qw + 0;  a.q1[0] = qw + 64;  a.o0[0] = tl3;          a.o1[0] = tl3 + NG;
    a.Ab[1] = rb_gene; a.Wb[1] = arWb;            a.bias[1] = arb;      a.N[1] = NG; a.BN[1] = 32;
    a.q0[1] = qw + 32; a.q1[1] = qw + 32;  a.o0[1] = tr3;          a.o1[1] = tr3;
    a.Ab[2] = lb_prot; a.Wb[2] = alWb + 64 * 128; a.bias[2] = alb + 64; a.N[2] = NP; a.BN[2] = 32;
    a.q0[2] = qw + 128; a.q1[2] = qw + 128; a.o0[2] = tl3 + 2 * NG; a.o1[2] = tl3 + 2 * NG;
    a.Ab[3] = rb_prot; a.Wb[3] = arWb + 32 * 128; a.bias[3] = arb + 32; a.N[3] = NP; a.BN[3] = 64;
    a.q0[3] = qw + 96; a.q1[3] = qw + 160; a.o0[3] = tr3 + NG;     a.o1[3] = tr3 + NG + NP;
    attn_proj_multi<<<dim3(NPG / 128, 4), blk, 0, stream>>>(a);
  }

  // ---- 3) CSR build (hist+rank -> scan -> scatter{d*256,w}) ----
  const int gridE3 = (3 * E + 255) / 256;
  hipMemsetAsync(deg, 0, (size_t)NT * sizeof(int), stream);
  hist3_kernel<<<gridE3, blk, 0, stream>>>(e_gg, e_gp, e_pp, deg, rank, E, NG);
  scanA_kernel<<<TILES, blk, 0, stream>>>(deg, offsets, tile_tot, NT);
  scanB_kernel<<<1, blk, 0, stream>>>(tile_tot, tile_pre, offsets, TILES, NT);
  scanC_kernel<<<TILES, blk, 0, stream>>>(offsets, tile_pre, NT);
  scatter3_kernel<<<gridE3, blk, 0, stream>>>(e_gg, e_gp, e_pp, rank, offsets,
                                              tl3, tr3, sharp, recs, E, NG, NP);

  // ---- 4) fused gather + relation combine (1 dispatch) ----
  gather_combine<<<(NG + NP + 15) / 16, blk, 0, stream>>>(
      rb_gene, rb_prot, lb_gene, lb_prot, offsets, recs,
      cgW, cgb, cpW, cpb, out_gene, out_prot, NG, NP);
}